// Round 5
// baseline (2527.793 us; speedup 1.0000x reference)
//
#include <hip/hip_runtime.h>
#include <hip/hip_bf16.h>
#include <hip/hip_cooperative_groups.h>

namespace cg = cooperative_groups;

#define FCD 2048
#define VEMBD 512
#define WEMBD 512
#define HD 512
#define AD 256
#define TVD 32
#define TCD 20
#define BCD 16
#define RPD 32
#define BD 512     // BCD*RPD
#define GLOVED 300

typedef __attribute__((ext_vector_type(8))) short short8v;
typedef __attribute__((ext_vector_type(4))) float f32x4;

__device__ __forceinline__ float sigf(float x) { return 1.0f / (1.0f + __expf(-x)); }
__device__ __forceinline__ float tanhfast(float x) {
    float e = __expf(2.0f * x);
    return 1.0f - 2.0f / (e + 1.0f);
}
__device__ __forceinline__ unsigned short f2bf(float x) {
    union { __hip_bfloat16 h; unsigned short u; } v;
    v.h = __float2bfloat16(x);
    return v.u;
}
__device__ __forceinline__ float b2f(unsigned short u) {
    union { unsigned int i; float f; } v;
    v.i = ((unsigned int)u) << 16;
    return v.f;
}

// ---------------------------------------------------------------------------
// fp32 -> bf16 elementwise convert
// ---------------------------------------------------------------------------
__launch_bounds__(256)
__global__ void conv_f2b_kernel(const float* __restrict__ src,
                                unsigned short* __restrict__ dst, int n4) {
    for (int i = blockIdx.x * 256 + threadIdx.x; i < n4; i += gridDim.x * 256) {
        const float4 v = ((const float4*)src)[i];
        ushort4 o;
        o.x = f2bf(v.x); o.y = f2bf(v.y); o.z = f2bf(v.z); o.w = f2bf(v.w);
        ((ushort4*)dst)[i] = o;
    }
}

// Permuted+concatenated vid gate weights: Wcat[g'][0:512]=Wih[g],[512:1024]=Whh[g]
// g' = (hc>>4)*64 + q*16 + (hc&15), g = q*512 + hc
__launch_bounds__(256)
__global__ void conv_wcat_perm_kernel(const float* __restrict__ Wih,
                                      const float* __restrict__ Whh,
                                      unsigned short* __restrict__ Wcat) {
    const int gp = blockIdx.x;
    const int q = (gp >> 4) & 3;
    const int hc = (gp >> 6) * 16 + (gp & 15);
    const long g = (long)(q * 512 + hc);
    for (int k = threadIdx.x; k < 512; k += 256) {
        Wcat[(long)gp * 1024 + k]       = f2bf(Wih[g * 512 + k]);
        Wcat[(long)gp * 1024 + 512 + k] = f2bf(Whh[g * 512 + k]);
    }
}

// Permuted cap Whh (same g' mapping), K=512
__launch_bounds__(256)
__global__ void conv_wcap_perm_kernel(const float* __restrict__ Whh,
                                      unsigned short* __restrict__ Wout) {
    const int gp = blockIdx.x;
    const int q = (gp >> 4) & 3;
    const int hc = (gp >> 6) * 16 + (gp & 15);
    const long g = (long)(q * 512 + hc);
    for (int k = threadIdx.x; k < 512; k += 256)
        Wout[(long)gp * 512 + k] = f2bf(Whh[g * 512 + k]);
}

__launch_bounds__(256)
__global__ void conv_bsum_kernel(const float* __restrict__ bih,
                                 const float* __restrict__ bhh,
                                 float* __restrict__ bsum) {
    const int gp = blockIdx.x * 256 + threadIdx.x;
    if (gp < 2048) {
        const int q = (gp >> 4) & 3;
        const int hc = (gp >> 6) * 16 + (gp & 15);
        const int g = q * 512 + hc;
        bsum[gp] = bih[g] + bhh[g];
    }
}

// ---------------------------------------------------------------------------
// MFMA bf16 GEMM, 128x128 tile. Grid: (x = m-tiles, y = n-tiles) so that
// concurrent blocks sweep m with shared B panel and A re-passes hit L3.
// ---------------------------------------------------------------------------
template<int AF32, int OBF>
__launch_bounds__(256)
__global__ void mfma_gemm128(const void* __restrict__ A,
                             const unsigned short* __restrict__ Bw,
                             const float* __restrict__ bias,
                             void* __restrict__ Cout,
                             int M, int N, int K)
{
    __shared__ unsigned short As[128][40];
    __shared__ unsigned short Bs[128][40];
    const int m0 = blockIdx.x * 128;
    const int n0 = blockIdx.y * 128;
    const int tid = threadIdx.x;
    const int lane = tid & 63;
    const int wid = tid >> 6;
    const int wm = (wid >> 1) * 64;
    const int wn = (wid & 1) * 64;
    const int lrow = lane & 15;
    const int lko = (lane >> 4) * 8;

    f32x4 acc[4][4] = {};

    for (int k0 = 0; k0 < K; k0 += 32) {
#pragma unroll
        for (int i = 0; i < 2; i++) {
            const int chunk = tid + i * 256;
            const int r = chunk >> 2;
            const int c8 = (chunk & 3) * 8;
            if (AF32) {
                const float* Af = (const float*)A + (long)(m0 + r) * K + k0 + c8;
                const float4 v0 = *(const float4*)Af;
                const float4 v1 = *(const float4*)(Af + 4);
                unsigned short* d = &As[r][c8];
                d[0] = f2bf(v0.x); d[1] = f2bf(v0.y); d[2] = f2bf(v0.z); d[3] = f2bf(v0.w);
                d[4] = f2bf(v1.x); d[5] = f2bf(v1.y); d[6] = f2bf(v1.z); d[7] = f2bf(v1.w);
            } else {
                *(short8v*)&As[r][c8] =
                    *(const short8v*)((const unsigned short*)A + (long)(m0 + r) * K + k0 + c8);
            }
            *(short8v*)&Bs[r][c8] =
                *(const short8v*)(Bw + (long)(n0 + r) * K + k0 + c8);
        }
        __syncthreads();
        short8v a[4], b[4];
#pragma unroll
        for (int mi = 0; mi < 4; mi++)
            a[mi] = *(const short8v*)&As[wm + mi * 16 + lrow][lko];
#pragma unroll
        for (int ni = 0; ni < 4; ni++)
            b[ni] = *(const short8v*)&Bs[wn + ni * 16 + lrow][lko];
#pragma unroll
        for (int mi = 0; mi < 4; mi++)
#pragma unroll
            for (int ni = 0; ni < 4; ni++)
                acc[mi][ni] = __builtin_amdgcn_mfma_f32_16x16x32_bf16(
                    a[mi], b[ni], acc[mi][ni], 0, 0, 0);
        __syncthreads();
    }

    const int rbase = (lane >> 4) * 4;
#pragma unroll
    for (int ni = 0; ni < 4; ni++) {
        const int col = n0 + wn + ni * 16 + lrow;
        const float bv = bias[col];
#pragma unroll
        for (int mi = 0; mi < 4; mi++) {
#pragma unroll
            for (int j = 0; j < 4; j++) {
                const long row = m0 + wm + mi * 16 + rbase + j;
                const float val = acc[mi][ni][j] + bv;
                if (OBF) ((unsigned short*)Cout)[row * N + col] = f2bf(val);
                else     ((float*)Cout)[row * N + col] = val;
            }
        }
    }
}

// ---------------------------------------------------------------------------
// Persistent fused LSTM chains (cooperative, 256 blocks x 256 threads).
// Block vb: vid tile (n0 = (vb&31)*64 g'-rows, b0 = (vb>>5)*64 batches).
// Wcat tile resident in LDS (129 KB). c-state + vid-mean in registers.
// Blocks 0..31 additionally run cap LSTM step t<20 (gate q = wave, B-frags
// register-resident; gate exchange via 4 KB LDS aliased on A staging buf).
// h ping-pongs through global; grid.sync() between steps.
// ---------------------------------------------------------------------------
__launch_bounds__(256, 1)
__global__ void fused_chains(const unsigned short* __restrict__ vidx,
                             const unsigned short* __restrict__ Wcat,
                             const float* __restrict__ bsum,
                             unsigned short* __restrict__ hv0,
                             unsigned short* __restrict__ hv1,
                             unsigned short* __restrict__ vidh,
                             float* __restrict__ out1,
                             const unsigned short* __restrict__ Wcapcat,
                             const float* __restrict__ xg,
                             const float* __restrict__ bhh_c,
                             unsigned short* __restrict__ hcap0,
                             unsigned short* __restrict__ hcap1,
                             float* __restrict__ caph)
{
    __shared__ unsigned short Wl[64][1032];      // 129 KB resident W tile
    __shared__ unsigned short Abuf[2][64][72];   // 18 KB A staging dbuf (aliased by cap)
    const int vb = blockIdx.x;
    const int n0 = (vb & 31) * 64;
    const int b0 = (vb >> 5) * 64;
    const int tid = threadIdx.x;
    const int lane = tid & 63;
    const int w = tid >> 6;
    const int lrow = lane & 15;
    const int lko = (lane >> 4) * 8;
    const int sr = tid >> 2;
    const int sc8 = (tid & 3) * 8;

    // stage resident W tile (64 x 1024 bf16)
#pragma unroll
    for (int it = 0; it < 32; it++) {
        const int idx = tid + it * 256;
        const int r = idx >> 7;
        const int c8 = (idx & 127) * 8;
        *(short8v*)&Wl[r][c8] = *(const short8v*)(Wcat + (long)(n0 + r) * 1024 + c8);
    }

    const bool iscap = (vb < 32);
    const int bt = tid >> 4;       // cap batch
    const int rt = tid & 15;       // cap hc offset
    const int hcg = vb * 16 + rt;  // cap global hc (valid if iscap)
    short8v capB[16];
    float bh0 = 0, bh1 = 0, bh2 = 0, bh3 = 0;
    if (iscap) {
#pragma unroll
        for (int ki = 0; ki < 16; ki++)
            capB[ki] = *(const short8v*)(Wcapcat + (long)(vb * 64 + w * 16 + lrow) * 512 + ki * 32 + lko);
        bh0 = bhh_c[hcg]; bh1 = bhh_c[512 + hcg];
        bh2 = bhh_c[1024 + hcg]; bh3 = bhh_c[1536 + hcg];
    }
    const float bs0 = bsum[n0 + lrow];
    const float bs1 = bsum[n0 + 16 + lrow];
    const float bs2 = bsum[n0 + 32 + lrow];
    const float bs3 = bsum[n0 + 48 + lrow];

    float cvid[4] = {0.f, 0.f, 0.f, 0.f};
    float macc[4] = {0.f, 0.f, 0.f, 0.f};
    float ccap_r = 0.f;

    __syncthreads();
    cg::grid_group grid = cg::this_grid();

    for (int t = 0; t < TVD; t++) {
        const unsigned short* hvin = (t & 1) ? hv1 : hv0;
        unsigned short* hvout = (t & 1) ? hv0 : hv1;
        const bool docap = iscap && (t < TCD);
        short8v capA[16];
        f32x4 cacc = {0.f, 0.f, 0.f, 0.f};
        if (docap) {
            const unsigned short* hcin = (t & 1) ? hcap1 : hcap0;
            unsigned short* Hc = &Abuf[0][0][0];   // [16][520] alias
#pragma unroll
            for (int i = 0; i < 4; i++) {
                const int idx = tid + i * 256;
                const int r = idx >> 6;
                const int c8 = (idx & 63) * 8;
                *(short8v*)(Hc + r * 520 + c8) = *(const short8v*)(hcin + r * 512 + c8);
            }
            __syncthreads();
#pragma unroll
            for (int ki = 0; ki < 16; ki++)
                capA[ki] = *(const short8v*)(Hc + lrow * 520 + ki * 32 + lko);
            __syncthreads();   // reads done before vid staging clobbers
#pragma unroll
            for (int ki = 0; ki < 16; ki++)
                cacc = __builtin_amdgcn_mfma_f32_16x16x32_bf16(capA[ki], capB[ki], cacc, 0, 0, 0);
        }

        // ---- vid: K = 1024 = [vx(512); h(512)], 16 chunks of 64, dbuf ----
        f32x4 acc[4] = {};
        {
            const unsigned short* srcr = vidx + ((long)(b0 + sr) * TVD + t) * 512;
            *(short8v*)&Abuf[0][sr][sc8]      = *(const short8v*)(srcr + sc8);
            *(short8v*)&Abuf[0][sr][sc8 + 32] = *(const short8v*)(srcr + sc8 + 32);
        }
        __syncthreads();
#pragma unroll 2
        for (int c = 0; c < 16; c++) {
            short8v p0, p1;
            if (c < 15) {
                const int kg = (c + 1) * 64;
                const unsigned short* srcr = (kg < 512)
                    ? vidx + ((long)(b0 + sr) * TVD + t) * 512 + kg
                    : hvin + (long)(b0 + sr) * 512 + (kg - 512);
                p0 = *(const short8v*)(srcr + sc8);
                p1 = *(const short8v*)(srcr + sc8 + 32);
            }
#pragma unroll
            for (int j = 0; j < 2; j++) {
                const short8v a = *(const short8v*)&Abuf[c & 1][w * 16 + lrow][j * 32 + lko];
#pragma unroll
                for (int ni = 0; ni < 4; ni++) {
                    const short8v b = *(const short8v*)&Wl[ni * 16 + lrow][c * 64 + j * 32 + lko];
                    acc[ni] = __builtin_amdgcn_mfma_f32_16x16x32_bf16(a, b, acc[ni], 0, 0, 0);
                }
            }
            if (c < 15) {
                *(short8v*)&Abuf[(c + 1) & 1][sr][sc8]      = p0;
                *(short8v*)&Abuf[(c + 1) & 1][sr][sc8 + 32] = p1;
                __syncthreads();
            }
        }
        // vid cell update (identical math/order to R4's vid_step_mfma)
        const int hc = (n0 >> 2) + lrow;
        const int rbase = (lane >> 4) * 4;
#pragma unroll
        for (int j = 0; j < 4; j++) {
            const long b = b0 + w * 16 + rbase + j;
            const float gi = acc[0][j] + bs0;
            const float gf = acc[1][j] + bs1;
            const float gg = acc[2][j] + bs2;
            const float go = acc[3][j] + bs3;
            const float ii = sigf(gi), ff = sigf(gf), g2 = tanhfast(gg), oo = sigf(go);
            const float cn = ff * cvid[j] + ii * g2;
            const float h = oo * tanhfast(cn);
            cvid[j] = cn;
            macc[j] += h;
            const unsigned short hb = f2bf(h);
            hvout[b * 512 + hc] = hb;
            vidh[(b * TVD + t) * 512 + hc] = hb;
        }

        if (docap) {
            __syncthreads();   // all waves done reading Abuf this step
            float* Lc = (float*)&Abuf[0][0][0];   // [4][16][16] gates exchange
#pragma unroll
            for (int j = 0; j < 4; j++)
                Lc[w * 256 + (rbase + j) * 16 + lrow] = cacc[j];
            __syncthreads();
            unsigned short* hcout = (t & 1) ? hcap0 : hcap1;
            const long xbase = (long)(bt * TCD + t) * 2048;
            const float gi = Lc[0 * 256 + bt * 16 + rt] + xg[xbase + hcg]        + bh0;
            const float gf = Lc[1 * 256 + bt * 16 + rt] + xg[xbase + 512 + hcg]  + bh1;
            const float gg = Lc[2 * 256 + bt * 16 + rt] + xg[xbase + 1024 + hcg] + bh2;
            const float go = Lc[3 * 256 + bt * 16 + rt] + xg[xbase + 1536 + hcg] + bh3;
            const float ii = sigf(gi), ff = sigf(gf), g2 = tanhfast(gg), oo = sigf(go);
            ccap_r = ff * ccap_r + ii * g2;
            const float h = oo * tanhfast(ccap_r);
            caph[(long)(bt * TCD + t) * 512 + hcg] = h;
            hcout[bt * 512 + hcg] = f2bf(h);
        }
        __threadfence();
        grid.sync();
    }

    // vid mean epilogue
    const int hc = (n0 >> 2) + lrow;
    const int rbase = (lane >> 4) * 4;
#pragma unroll
    for (int j = 0; j < 4; j++) {
        const long b = b0 + w * 16 + rbase + j;
        out1[b * 512 + hc] = macc[j] * (1.0f / TVD);
    }
}

// ---------------------------------------------------------------------------
// Generic fp32 tiled GEMM (cap front path + c_lin)
// ---------------------------------------------------------------------------
__launch_bounds__(256)
__global__ void gemm_bias_kernel(const float* __restrict__ A,
                                 const float* __restrict__ Bw,
                                 const float* __restrict__ bias,
                                 float* __restrict__ C,
                                 int M, int N, int K) {
    __shared__ float As[16][68];
    __shared__ float Bs[16][68];
    const int n0 = blockIdx.x * 64;
    const int m0 = blockIdx.y * 64;
    const int tid = threadIdx.x;
    const int tx = tid & 15;
    const int ty = tid >> 4;
    const int lrow = tid >> 2;
    const int lk4 = (tid & 3) * 4;

    float acc[4][4] = {};

    for (int k0 = 0; k0 < K; k0 += 16) {
        {
            const float* src = A + (long)(m0 + lrow) * K + k0 + lk4;
            float4 v;
            if (k0 + 16 <= K) v = *(const float4*)src;
            else {
                v.x = (k0 + lk4 + 0 < K) ? src[0] : 0.f;
                v.y = (k0 + lk4 + 1 < K) ? src[1] : 0.f;
                v.z = (k0 + lk4 + 2 < K) ? src[2] : 0.f;
                v.w = (k0 + lk4 + 3 < K) ? src[3] : 0.f;
            }
            As[lk4 + 0][lrow] = v.x; As[lk4 + 1][lrow] = v.y;
            As[lk4 + 2][lrow] = v.z; As[lk4 + 3][lrow] = v.w;
        }
        {
            const float* src = Bw + (long)(n0 + lrow) * K + k0 + lk4;
            float4 v;
            if (k0 + 16 <= K) v = *(const float4*)src;
            else {
                v.x = (k0 + lk4 + 0 < K) ? src[0] : 0.f;
                v.y = (k0 + lk4 + 1 < K) ? src[1] : 0.f;
                v.z = (k0 + lk4 + 2 < K) ? src[2] : 0.f;
                v.w = (k0 + lk4 + 3 < K) ? src[3] : 0.f;
            }
            Bs[lk4 + 0][lrow] = v.x; Bs[lk4 + 1][lrow] = v.y;
            Bs[lk4 + 2][lrow] = v.z; Bs[lk4 + 3][lrow] = v.w;
        }
        __syncthreads();
#pragma unroll
        for (int kk = 0; kk < 16; kk++) {
            const float4 av = *(const float4*)&As[kk][ty * 4];
            const float4 bv = *(const float4*)&Bs[kk][tx * 4];
            acc[0][0] += av.x * bv.x; acc[0][1] += av.x * bv.y; acc[0][2] += av.x * bv.z; acc[0][3] += av.x * bv.w;
            acc[1][0] += av.y * bv.x; acc[1][1] += av.y * bv.y; acc[1][2] += av.y * bv.z; acc[1][3] += av.y * bv.w;
            acc[2][0] += av.z * bv.x; acc[2][1] += av.z * bv.y; acc[2][2] += av.z * bv.z; acc[2][3] += av.z * bv.w;
            acc[3][0] += av.w * bv.x; acc[3][1] += av.w * bv.y; acc[3][2] += av.w * bv.z; acc[3][3] += av.w * bv.w;
        }
        __syncthreads();
    }

    const float b0v = bias[n0 + tx * 4 + 0];
    const float b1v = bias[n0 + tx * 4 + 1];
    const float b2v = bias[n0 + tx * 4 + 2];
    const float b3v = bias[n0 + tx * 4 + 3];
#pragma unroll
    for (int i = 0; i < 4; i++) {
        float* dst = C + (long)(m0 + ty * 4 + i) * N + n0 + tx * 4;
        dst[0] = acc[i][0] + b0v;
        dst[1] = acc[i][1] + b1v;
        dst[2] = acc[i][2] + b2v;
        dst[3] = acc[i][3] + b3v;
    }
}

// ---------------------------------------------------------------------------
// Attention: one block per (bc, rp); scores -> masked softmax -> wbar mean_v.
// ---------------------------------------------------------------------------
__launch_bounds__(256)
__global__ void attn_kernel(const float* __restrict__ v_lin,
                            const float* __restrict__ c_lin,
                            const float* __restrict__ W_att,
                            const float* __restrict__ b_att,
                            const int* __restrict__ cap_len,
                            float* __restrict__ wbar)
{
    const int br = blockIdx.x;
    const int bc = br >> 5;
    const int tid = threadIdx.x;
    const int lane = tid & 63;
    const int wv = tid >> 6;
    __shared__ float cl[TCD][AD];
    __shared__ float vl[AD];
    __shared__ float sl[TVD][TCD];

    for (int tt = 0; tt < TCD; tt++)
        cl[tt][tid] = c_lin[(long)(bc * TCD + tt) * AD + tid];
    const float wa0 = W_att[lane];
    const float wa1 = W_att[64 + lane];
    const float wa2 = W_att[128 + lane];
    const float wa3 = W_att[192 + lane];
    const float batt = b_att[0];
    __syncthreads();

    for (int v = 0; v < TVD; v++) {
        vl[tid] = v_lin[((long)br * TVD + v) * AD + tid];
        __syncthreads();
        const float v0 = vl[lane], v1 = vl[64 + lane], v2 = vl[128 + lane], v3 = vl[192 + lane];
#pragma unroll
        for (int dt = 0; dt < 5; dt++) {
            const int t = wv * 5 + dt;
            float s = tanhfast(v0 + cl[t][lane]) * wa0
                    + tanhfast(v1 + cl[t][64 + lane]) * wa1
                    + tanhfast(v2 + cl[t][128 + lane]) * wa2
                    + tanhfast(v3 + cl[t][192 + lane]) * wa3;
            for (int off = 32; off > 0; off >>= 1) s += __shfl_down(s, off, 64);
            if (lane == 0) sl[v][t] = s + batt;
        }
        __syncthreads();
    }

    int L = cap_len[bc];
    if (L < 1) L = 1;
    if (tid < TVD) {
        const int v = tid;
        float m = -1e30f;
        for (int t = 0; t < TCD; t++)
            if (t < L) m = fmaxf(m, sl[v][t]);
        float sum = 0.f;
        for (int t = 0; t < TCD; t++)
            if (t < L) sum += __expf(sl[v][t] - m);
        const float inv = 1.f / sum;
        for (int t = 0; t < TCD; t++)
            sl[v][t] = (t < L) ? __expf(sl[v][t] - m) * inv : 0.f;
    }
    __syncthreads();
    if (tid < TCD) {
        float s = 0.f;
        for (int v = 0; v < TVD; v++) s += sl[v][tid];
        wbar[(long)br * TCD + tid] = s * (1.0f / TVD);
    }
}

__launch_bounds__(256)
__global__ void capftr_kernel(const float* __restrict__ wbar,
                              const float* __restrict__ cap_h,
                              float* __restrict__ out2)
{
    const int idx = blockIdx.x * 256 + threadIdx.x;
    const int h = idx & 511;
    const int br = idx >> 9;
    const int bc = br >> 5;
    float s = 0.f;
#pragma unroll
    for (int t = 0; t < TCD; t++)
        s += wbar[br * TCD + t] * cap_h[(long)(bc * TCD + t) * HD + h];
    out2[idx] = s;
}

extern "C" void kernel_launch(void* const* d_in, const int* in_sizes, int n_in,
                              void* d_out, int out_size, void* d_ws, size_t ws_size,
                              hipStream_t stream) {
    const float* video_fc      = (const float*)d_in[0];
    const float* video_caption = (const float*)d_in[1];
    const int*   cap_len       = (const int*)d_in[2];
    const float* W_vemb = (const float*)d_in[3];
    const float* b_vemb = (const float*)d_in[4];
    const float* W_wemb = (const float*)d_in[5];
    const float* b_wemb = (const float*)d_in[6];
    const float* Wih_v  = (const float*)d_in[7];
    const float* Whh_v  = (const float*)d_in[8];
    const float* bih_v  = (const float*)d_in[9];
    const float* bhh_v  = (const float*)d_in[10];
    const float* Wih_c  = (const float*)d_in[11];
    const float* Whh_c  = (const float*)d_in[12];
    const float* bih_c  = (const float*)d_in[13];
    const float* bhh_c  = (const float*)d_in[14];
    const float* W_vid  = (const float*)d_in[15];
    const float* b_vid  = (const float*)d_in[16];
    const float* W_sen  = (const float*)d_in[17];
    const float* b_sen  = (const float*)d_in[18];
    const float* W_att  = (const float*)d_in[19];
    const float* b_att  = (const float*)d_in[20];

    float* out1 = (float*)d_out;            // vid_mean
    float* out2 = out1 + BD * HD;           // cap_ftr_mean

    float* ws = (float*)d_ws;
    size_t off = 0;
    auto alloc = [&](size_t nfloats) {
        float* p = ws + off;
        off += (nfloats + 63) & ~(size_t)63;
        return p;
    };
    unsigned short* vidx_bf   = (unsigned short*)alloc((size_t)BD * TVD * VEMBD / 2);
    unsigned short* vidh_bf   = (unsigned short*)alloc((size_t)BD * TVD * HD / 2);
    unsigned short* hv0       = (unsigned short*)alloc((size_t)BD * HD / 2);
    unsigned short* hv1       = (unsigned short*)alloc((size_t)BD * HD / 2);
    unsigned short* hcap0     = (unsigned short*)alloc((size_t)BCD * HD / 2);
    unsigned short* hcap1     = (unsigned short*)alloc((size_t)BCD * HD / 2);
    float* v_lin    = alloc((size_t)BD * TVD * AD);
    unsigned short* Wvemb_bf  = (unsigned short*)alloc((size_t)VEMBD * FCD / 2);
    unsigned short* Wvid_bf   = (unsigned short*)alloc((size_t)AD * HD / 2);
    unsigned short* Wcat_bf   = (unsigned short*)alloc((size_t)2048 * 1024 / 2);
    unsigned short* Wcapcat_bf= (unsigned short*)alloc((size_t)2048 * 512 / 2);
    float* bsum     = alloc(2048);
    float* cap_x    = alloc((size_t)BCD * TCD * WEMBD);
    float* xg_c     = alloc((size_t)BCD * TCD * 4 * HD);
    float* cap_h    = alloc((size_t)BCD * TCD * HD);
    float* c_lin    = alloc((size_t)BCD * TCD * AD);
    float* wbar     = alloc((size_t)BD * TCD);

    hipMemsetAsync(hv0, 0, (size_t)BD * HD * sizeof(unsigned short), stream);
    hipMemsetAsync(hcap0, 0, (size_t)BCD * HD * sizeof(unsigned short), stream);

    // weight conversions
    conv_f2b_kernel<<<512, 256, 0, stream>>>(W_vemb, Wvemb_bf, VEMBD * FCD / 4);
    conv_f2b_kernel<<<128, 256, 0, stream>>>(W_vid, Wvid_bf, AD * HD / 4);
    conv_wcat_perm_kernel<<<2048, 256, 0, stream>>>(Wih_v, Whh_v, Wcat_bf);
    conv_wcap_perm_kernel<<<2048, 256, 0, stream>>>(Whh_c, Wcapcat_bf);
    conv_bsum_kernel<<<8, 256, 0, stream>>>(bih_v, bhh_v, bsum);

    // caption front path (fp32): cap_x, then xg = cap_x@Wih_c^T + bih_c
    gemm_bias_kernel<<<dim3(WEMBD / 64, (BCD * TCD) / 64), 256, 0, stream>>>(
        video_caption, W_wemb, b_wemb, cap_x, BCD * TCD, WEMBD, GLOVED);
    gemm_bias_kernel<<<dim3((4 * HD) / 64, (BCD * TCD) / 64), 256, 0, stream>>>(
        cap_x, Wih_c, bih_c, xg_c, BCD * TCD, 4 * HD, WEMBD);

    // vid_x GEMM (bf16 MFMA, m-fastest grid for A locality)
    mfma_gemm128<1, 1><<<dim3((BD * TVD) / 128, VEMBD / 128), 256, 0, stream>>>(
        video_fc, Wvemb_bf, b_vemb, vidx_bf, BD * TVD, VEMBD, FCD);

    // fused persistent LSTM chains (vid 32 steps + cap 20 steps)
    {
        void* kargs[] = {
            (void*)&vidx_bf, (void*)&Wcat_bf, (void*)&bsum,
            (void*)&hv0, (void*)&hv1, (void*)&vidh_bf, (void*)&out1,
            (void*)&Wcapcat_bf, (void*)&xg_c, (void*)&bhh_c,
            (void*)&hcap0, (void*)&hcap1, (void*)&cap_h
        };
        hipLaunchCooperativeKernel((void*)fused_chains, dim3(256), dim3(256),
                                   kargs, 0, stream);
    }

    // post GEMMs
    gemm_bias_kernel<<<dim3(AD / 64, (BCD * TCD) / 64), 256, 0, stream>>>(
        cap_h, W_sen, b_sen, c_lin, BCD * TCD, AD, HD);
    mfma_gemm128<0, 0><<<dim3((BD * TVD) / 128, AD / 128), 256, 0, stream>>>(
        vidh_bf, Wvid_bf, b_vid, v_lin, BD * TVD, AD, HD);

    // attention + outputs
    attn_kernel<<<BD, 256, 0, stream>>>(v_lin, c_lin, W_att, b_att, cap_len, wbar);
    capftr_kernel<<<(BD * HD) / 256, 256, 0, stream>>>(wbar, cap_h, out2);
}

// Round 6
// 1003.400 us; speedup vs baseline: 2.5192x; 2.5192x over previous
//
#include <hip/hip_runtime.h>
#include <hip/hip_bf16.h>

#define FCD 2048
#define VEMBD 512
#define WEMBD 512
#define HD 512
#define AD 256
#define TVD 32
#define TCD 20
#define BCD 16
#define RPD 32
#define BD 512     // BCD*RPD
#define GLOVED 300

typedef __attribute__((ext_vector_type(8))) short short8v;
typedef __attribute__((ext_vector_type(4))) float f32x4;

__device__ __forceinline__ float sigf(float x) { return 1.0f / (1.0f + __expf(-x)); }
__device__ __forceinline__ float tanhfast(float x) {
    float e = __expf(2.0f * x);
    return 1.0f - 2.0f / (e + 1.0f);
}
__device__ __forceinline__ unsigned short f2bf(float x) {
    union { __hip_bfloat16 h; unsigned short u; } v;
    v.h = __float2bfloat16(x);
    return v.u;
}
__device__ __forceinline__ float b2f(unsigned short u) {
    union { unsigned int i; float f; } v;
    v.i = ((unsigned int)u) << 16;
    return v.f;
}

// ---------------------------------------------------------------------------
// fp32 -> bf16 elementwise convert
// ---------------------------------------------------------------------------
__launch_bounds__(256)
__global__ void conv_f2b_kernel(const float* __restrict__ src,
                                unsigned short* __restrict__ dst, int n4) {
    for (int i = blockIdx.x * 256 + threadIdx.x; i < n4; i += gridDim.x * 256) {
        const float4 v = ((const float4*)src)[i];
        ushort4 o;
        o.x = f2bf(v.x); o.y = f2bf(v.y); o.z = f2bf(v.z); o.w = f2bf(v.w);
        ((ushort4*)dst)[i] = o;
    }
}

// Permuted+concatenated gate weights: Wcat[g'][0:512]=Wih[g], [512:1024]=Whh[g]
// g' = (hc>>4)*64 + q*16 + (hc&15), g = q*512 + hc. bf16 out.
__launch_bounds__(256)
__global__ void conv_wcat_perm_kernel(const float* __restrict__ Wih,
                                      const float* __restrict__ Whh,
                                      unsigned short* __restrict__ Wcat) {
    const int gp = blockIdx.x;
    const int q = (gp >> 4) & 3;
    const int hc = (gp >> 6) * 16 + (gp & 15);
    const long g = (long)(q * 512 + hc);
    for (int k = threadIdx.x; k < 512; k += 256) {
        Wcat[(long)gp * 1024 + k]       = f2bf(Wih[g * 512 + k]);
        Wcat[(long)gp * 1024 + 512 + k] = f2bf(Whh[g * 512 + k]);
    }
}

__launch_bounds__(256)
__global__ void conv_bsum_kernel(const float* __restrict__ bih,
                                 const float* __restrict__ bhh,
                                 float* __restrict__ bsum) {
    const int gp = blockIdx.x * 256 + threadIdx.x;
    if (gp < 2048) {
        const int q = (gp >> 4) & 3;
        const int hc = (gp >> 6) * 16 + (gp & 15);
        const int g = q * 512 + hc;
        bsum[gp] = bih[g] + bhh[g];
    }
}

// ---------------------------------------------------------------------------
// MFMA bf16 GEMM, 128x128 tile. Grid: (x = m-tiles fastest, y = n-tiles) so
// concurrent blocks sweep m sharing a B panel; A re-passes hit L3.
// ---------------------------------------------------------------------------
template<int AF32, int OBF>
__launch_bounds__(256)
__global__ void mfma_gemm128(const void* __restrict__ A,
                             const unsigned short* __restrict__ Bw,
                             const float* __restrict__ bias,
                             void* __restrict__ Cout,
                             int M, int N, int K)
{
    __shared__ unsigned short As[128][40];
    __shared__ unsigned short Bs[128][40];
    const int m0 = blockIdx.x * 128;
    const int n0 = blockIdx.y * 128;
    const int tid = threadIdx.x;
    const int lane = tid & 63;
    const int wid = tid >> 6;
    const int wm = (wid >> 1) * 64;
    const int wn = (wid & 1) * 64;
    const int lrow = lane & 15;
    const int lko = (lane >> 4) * 8;

    f32x4 acc[4][4] = {};

    for (int k0 = 0; k0 < K; k0 += 32) {
#pragma unroll
        for (int i = 0; i < 2; i++) {
            const int chunk = tid + i * 256;
            const int r = chunk >> 2;
            const int c8 = (chunk & 3) * 8;
            if (AF32) {
                const float* Af = (const float*)A + (long)(m0 + r) * K + k0 + c8;
                const float4 v0 = *(const float4*)Af;
                const float4 v1 = *(const float4*)(Af + 4);
                unsigned short* d = &As[r][c8];
                d[0] = f2bf(v0.x); d[1] = f2bf(v0.y); d[2] = f2bf(v0.z); d[3] = f2bf(v0.w);
                d[4] = f2bf(v1.x); d[5] = f2bf(v1.y); d[6] = f2bf(v1.z); d[7] = f2bf(v1.w);
            } else {
                *(short8v*)&As[r][c8] =
                    *(const short8v*)((const unsigned short*)A + (long)(m0 + r) * K + k0 + c8);
            }
            *(short8v*)&Bs[r][c8] =
                *(const short8v*)(Bw + (long)(n0 + r) * K + k0 + c8);
        }
        __syncthreads();
        short8v a[4], b[4];
#pragma unroll
        for (int mi = 0; mi < 4; mi++)
            a[mi] = *(const short8v*)&As[wm + mi * 16 + lrow][lko];
#pragma unroll
        for (int ni = 0; ni < 4; ni++)
            b[ni] = *(const short8v*)&Bs[wn + ni * 16 + lrow][lko];
#pragma unroll
        for (int mi = 0; mi < 4; mi++)
#pragma unroll
            for (int ni = 0; ni < 4; ni++)
                acc[mi][ni] = __builtin_amdgcn_mfma_f32_16x16x32_bf16(
                    a[mi], b[ni], acc[mi][ni], 0, 0, 0);
        __syncthreads();
    }

    const int rbase = (lane >> 4) * 4;
#pragma unroll
    for (int ni = 0; ni < 4; ni++) {
        const int col = n0 + wn + ni * 16 + lrow;
        const float bv = bias[col];
#pragma unroll
        for (int mi = 0; mi < 4; mi++) {
#pragma unroll
            for (int j = 0; j < 4; j++) {
                const long row = m0 + wm + mi * 16 + rbase + j;
                const float val = acc[mi][ni][j] + bv;
                if (OBF) ((unsigned short*)Cout)[row * N + col] = f2bf(val);
                else     ((float*)Cout)[row * N + col] = val;
            }
        }
    }
}

// ---------------------------------------------------------------------------
// Video LSTM step (bf16 MFMA): gates[b][g'] = [vid_x[b,t], h_in[b]] @ Wcat^T
// + bsum, then in-register cell update. 64 batch x 64 g' tile, 256 thr.
// BK=128 (8 chunks), register-prefetch staging: chunk c+1's global loads
// issue before chunk c's MFMAs, LDS write after the barrier (latency hidden
// under MFMA+sync). Numerics identical to the R4 BK=32 version (same k order).
// ---------------------------------------------------------------------------
__launch_bounds__(256)
__global__ void vid_step_mfma(const unsigned short* __restrict__ vx,   // [B*TV][512] bf16
                              const unsigned short* __restrict__ h_in, // [B][512] bf16
                              const unsigned short* __restrict__ Wcat, // [2048][1024] bf16 g'
                              const float* __restrict__ bsum,          // [2048] g'
                              float* __restrict__ c_state,             // [B][512] f32
                              unsigned short* __restrict__ h_out,      // [B][512] bf16
                              unsigned short* __restrict__ vid_h,      // [B*TV][512] bf16
                              int t)
{
    __shared__ unsigned short As[64][136];    // 17.4 KB (pad 8: 2-way bank alias = free)
    __shared__ unsigned short Ws2[64][136];
    const int n0 = blockIdx.x * 64;   // g' base
    const int b0 = blockIdx.y * 64;   // batch base
    const int tid = threadIdx.x;
    const int lane = tid & 63;
    const int w = tid >> 6;
    const int lrow = lane & 15;
    const int lko = (lane >> 4) * 8;
    const int sr = tid >> 2;          // staging row 0..63
    const int sc = (tid & 3) * 32;    // staging col base (64 B/thread contiguous)

    f32x4 acc[4] = {};

    const unsigned short* arow_vx = vx + ((long)(b0 + sr) * TVD + t) * 512;
    const unsigned short* arow_h  = h_in + (long)(b0 + sr) * 512;
    const unsigned short* wrow    = Wcat + (long)(n0 + sr) * 1024;

    // stage chunk 0 (k 0..127, all vx side)
#pragma unroll
    for (int i = 0; i < 4; i++) {
        *(short8v*)&As[sr][sc + i * 8]  = *(const short8v*)(arow_vx + sc + i * 8);
        *(short8v*)&Ws2[sr][sc + i * 8] = *(const short8v*)(wrow + sc + i * 8);
    }
    __syncthreads();

    short8v pa[4], pw[4];
    for (int c = 0; c < 8; c++) {
        if (c < 7) {
            const int k0 = (c + 1) * 128;
            const unsigned short* ap = (k0 < 512) ? (arow_vx + k0 + sc)
                                                  : (arow_h + (k0 - 512) + sc);
            const unsigned short* wp = wrow + k0 + sc;
#pragma unroll
            for (int i = 0; i < 4; i++) {
                pa[i] = *(const short8v*)(ap + i * 8);
                pw[i] = *(const short8v*)(wp + i * 8);
            }
        }
#pragma unroll
        for (int kk = 0; kk < 4; kk++) {
            const short8v a = *(const short8v*)&As[w * 16 + lrow][kk * 32 + lko];
#pragma unroll
            for (int ni = 0; ni < 4; ni++) {
                const short8v b = *(const short8v*)&Ws2[ni * 16 + lrow][kk * 32 + lko];
                acc[ni] = __builtin_amdgcn_mfma_f32_16x16x32_bf16(a, b, acc[ni], 0, 0, 0);
            }
        }
        __syncthreads();
        if (c < 7) {
#pragma unroll
            for (int i = 0; i < 4; i++) {
                *(short8v*)&As[sr][sc + i * 8]  = pa[i];
                *(short8v*)&Ws2[sr][sc + i * 8] = pw[i];
            }
            __syncthreads();
        }
    }

    const int hc = (n0 >> 2) + lrow;
    const int rbase = (lane >> 4) * 4;
    const float bs0 = bsum[n0 + lrow];
    const float bs1 = bsum[n0 + 16 + lrow];
    const float bs2 = bsum[n0 + 32 + lrow];
    const float bs3 = bsum[n0 + 48 + lrow];
#pragma unroll
    for (int j = 0; j < 4; j++) {
        const long b = b0 + w * 16 + rbase + j;
        const float gi = acc[0][j] + bs0;
        const float gf = acc[1][j] + bs1;
        const float gg = acc[2][j] + bs2;
        const float go = acc[3][j] + bs3;
        const float c_old = c_state[b * 512 + hc];
        const float ii = sigf(gi), ff = sigf(gf), g2 = tanhfast(gg), oo = sigf(go);
        const float cn = ff * c_old + ii * g2;
        const float h = oo * tanhfast(cn);
        c_state[b * 512 + hc] = cn;
        h_out[b * 512 + hc] = f2bf(h);
        vid_h[(b * TVD + t) * 512 + hc] = f2bf(h);
    }
}

// ---------------------------------------------------------------------------
// Generic fp32 tiled GEMM (cap path only)
// ---------------------------------------------------------------------------
__launch_bounds__(256)
__global__ void gemm_bias_kernel(const float* __restrict__ A,
                                 const float* __restrict__ Bw,
                                 const float* __restrict__ bias,
                                 float* __restrict__ C,
                                 int M, int N, int K) {
    __shared__ float As[16][68];
    __shared__ float Bs[16][68];
    const int n0 = blockIdx.x * 64;
    const int m0 = blockIdx.y * 64;
    const int tid = threadIdx.x;
    const int tx = tid & 15;
    const int ty = tid >> 4;
    const int lrow = tid >> 2;
    const int lk4 = (tid & 3) * 4;

    float acc[4][4] = {};

    for (int k0 = 0; k0 < K; k0 += 16) {
        {
            const float* src = A + (long)(m0 + lrow) * K + k0 + lk4;
            float4 v;
            if (k0 + 16 <= K) v = *(const float4*)src;
            else {
                v.x = (k0 + lk4 + 0 < K) ? src[0] : 0.f;
                v.y = (k0 + lk4 + 1 < K) ? src[1] : 0.f;
                v.z = (k0 + lk4 + 2 < K) ? src[2] : 0.f;
                v.w = (k0 + lk4 + 3 < K) ? src[3] : 0.f;
            }
            As[lk4 + 0][lrow] = v.x; As[lk4 + 1][lrow] = v.y;
            As[lk4 + 2][lrow] = v.z; As[lk4 + 3][lrow] = v.w;
        }
        {
            const float* src = Bw + (long)(n0 + lrow) * K + k0 + lk4;
            float4 v;
            if (k0 + 16 <= K) v = *(const float4*)src;
            else {
                v.x = (k0 + lk4 + 0 < K) ? src[0] : 0.f;
                v.y = (k0 + lk4 + 1 < K) ? src[1] : 0.f;
                v.z = (k0 + lk4 + 2 < K) ? src[2] : 0.f;
                v.w = (k0 + lk4 + 3 < K) ? src[3] : 0.f;
            }
            Bs[lk4 + 0][lrow] = v.x; Bs[lk4 + 1][lrow] = v.y;
            Bs[lk4 + 2][lrow] = v.z; Bs[lk4 + 3][lrow] = v.w;
        }
        __syncthreads();
#pragma unroll
        for (int kk = 0; kk < 16; kk++) {
            const float4 av = *(const float4*)&As[kk][ty * 4];
            const float4 bv = *(const float4*)&Bs[kk][tx * 4];
            acc[0][0] += av.x * bv.x; acc[0][1] += av.x * bv.y; acc[0][2] += av.x * bv.z; acc[0][3] += av.x * bv.w;
            acc[1][0] += av.y * bv.x; acc[1][1] += av.y * bv.y; acc[1][2] += av.y * bv.z; acc[1][3] += av.y * bv.w;
            acc[2][0] += av.z * bv.x; acc[2][1] += av.z * bv.y; acc[2][2] += av.z * bv.z; acc[2][3] += av.z * bv.w;
            acc[3][0] += av.w * bv.x; acc[3][1] += av.w * bv.y; acc[3][2] += av.w * bv.z; acc[3][3] += av.w * bv.w;
        }
        __syncthreads();
    }

    const float b0v = bias[n0 + tx * 4 + 0];
    const float b1v = bias[n0 + tx * 4 + 1];
    const float b2v = bias[n0 + tx * 4 + 2];
    const float b3v = bias[n0 + tx * 4 + 3];
#pragma unroll
    for (int i = 0; i < 4; i++) {
        float* dst = C + (long)(m0 + ty * 4 + i) * N + n0 + tx * 4;
        dst[0] = acc[i][0] + b0v;
        dst[1] = acc[i][1] + b1v;
        dst[2] = acc[i][2] + b2v;
        dst[3] = acc[i][3] + b3v;
    }
}

// ---------------------------------------------------------------------------
// Caption LSTM step (fp32, small): 32 blocks x 256 threads.
// ---------------------------------------------------------------------------
__launch_bounds__(256)
__global__ void cap_step_kernel(const float* __restrict__ xg,
                                const float* __restrict__ Whh,
                                const float* __restrict__ bhh,
                                const float* __restrict__ h_in,
                                float* __restrict__ h_out,
                                float* __restrict__ c_state,
                                float* __restrict__ cap_h,
                                int t)
{
    __shared__ float Ws[64][68];
    __shared__ float Hsh[16][68];
    const int h0 = blockIdx.x * 16;
    const int tid = threadIdx.x;
    const int tx = tid & 15;
    const int ty = tid >> 4;
    const int lrow = tid >> 2;
    const int lq = tid & 3;

    float acc[4] = {};

    for (int k0 = 0; k0 < 512; k0 += 64) {
        {
            const int q = lrow >> 4;
            const int hcc = lrow & 15;
            const float* src = Whh + (long)(q * 512 + h0 + hcc) * 512 + k0 + lq * 16;
            const int col = hcc * 4 + q;
#pragma unroll
            for (int j = 0; j < 4; j++) {
                const float4 v = *(const float4*)(src + j * 4);
                Ws[lq * 16 + j * 4 + 0][col] = v.x;
                Ws[lq * 16 + j * 4 + 1][col] = v.y;
                Ws[lq * 16 + j * 4 + 2][col] = v.z;
                Ws[lq * 16 + j * 4 + 3][col] = v.w;
            }
        }
        {
            const int lb = tid >> 4;
            const int lk4 = (tid & 15) * 4;
            *(float4*)&Hsh[lb][lk4] = *(const float4*)(h_in + (long)lb * 512 + k0 + lk4);
        }
        __syncthreads();
#pragma unroll
        for (int kq = 0; kq < 16; kq++) {
            const float4 h4 = *(const float4*)&Hsh[ty][kq * 4];
            const float4 w0 = *(const float4*)&Ws[kq * 4 + 0][tx * 4];
            const float4 w1 = *(const float4*)&Ws[kq * 4 + 1][tx * 4];
            const float4 w2 = *(const float4*)&Ws[kq * 4 + 2][tx * 4];
            const float4 w3 = *(const float4*)&Ws[kq * 4 + 3][tx * 4];
            acc[0] += h4.x * w0.x + h4.y * w1.x + h4.z * w2.x + h4.w * w3.x;
            acc[1] += h4.x * w0.y + h4.y * w1.y + h4.z * w2.y + h4.w * w3.y;
            acc[2] += h4.x * w0.z + h4.y * w1.z + h4.z * w2.z + h4.w * w3.z;
            acc[3] += h4.x * w0.w + h4.y * w1.w + h4.z * w2.w + h4.w * w3.w;
        }
        __syncthreads();
    }

    const int hc = h0 + tx;
    const long xrow = (long)(ty * TCD + t) * 2048;
    const float gi = acc[0] + xg[xrow + hc]        + bhh[hc];
    const float gf = acc[1] + xg[xrow + 512 + hc]  + bhh[512 + hc];
    const float gg = acc[2] + xg[xrow + 1024 + hc] + bhh[1024 + hc];
    const float go = acc[3] + xg[xrow + 1536 + hc] + bhh[1536 + hc];
    const float c_old = c_state[(long)ty * 512 + hc];
    const float ii = sigf(gi), ff = sigf(gf), g2 = tanhfast(gg), oo = sigf(go);
    const float c = ff * c_old + ii * g2;
    const float h = oo * tanhfast(c);
    c_state[(long)ty * 512 + hc] = c;
    h_out[(long)ty * 512 + hc] = h;
    cap_h[(long)(ty * TCD + t) * 512 + hc] = h;
}

// ---------------------------------------------------------------------------
// Attention: one block per (bc, rp); scores -> masked softmax -> wbar mean_v.
// ---------------------------------------------------------------------------
__launch_bounds__(256)
__global__ void attn_kernel(const float* __restrict__ v_lin,
                            const float* __restrict__ c_lin,
                            const float* __restrict__ W_att,
                            const float* __restrict__ b_att,
                            const int* __restrict__ cap_len,
                            float* __restrict__ wbar)
{
    const int br = blockIdx.x;
    const int bc = br >> 5;
    const int tid = threadIdx.x;
    const int lane = tid & 63;
    const int wv = tid >> 6;
    __shared__ float cl[TCD][AD];
    __shared__ float vl[AD];
    __shared__ float sl[TVD][TCD];

    for (int tt = 0; tt < TCD; tt++)
        cl[tt][tid] = c_lin[(long)(bc * TCD + tt) * AD + tid];
    const float wa0 = W_att[lane];
    const float wa1 = W_att[64 + lane];
    const float wa2 = W_att[128 + lane];
    const float wa3 = W_att[192 + lane];
    const float batt = b_att[0];
    __syncthreads();

    for (int v = 0; v < TVD; v++) {
        vl[tid] = v_lin[((long)br * TVD + v) * AD + tid];
        __syncthreads();
        const float v0 = vl[lane], v1 = vl[64 + lane], v2 = vl[128 + lane], v3 = vl[192 + lane];
#pragma unroll
        for (int dt = 0; dt < 5; dt++) {
            const int t = wv * 5 + dt;
            float s = tanhfast(v0 + cl[t][lane]) * wa0
                    + tanhfast(v1 + cl[t][64 + lane]) * wa1
                    + tanhfast(v2 + cl[t][128 + lane]) * wa2
                    + tanhfast(v3 + cl[t][192 + lane]) * wa3;
            for (int off = 32; off > 0; off >>= 1) s += __shfl_down(s, off, 64);
            if (lane == 0) sl[v][t] = s + batt;
        }
        __syncthreads();
    }

    int L = cap_len[bc];
    if (L < 1) L = 1;
    if (tid < TVD) {
        const int v = tid;
        float m = -1e30f;
        for (int t = 0; t < TCD; t++)
            if (t < L) m = fmaxf(m, sl[v][t]);
        float sum = 0.f;
        for (int t = 0; t < TCD; t++)
            if (t < L) sum += __expf(sl[v][t] - m);
        const float inv = 1.f / sum;
        for (int t = 0; t < TCD; t++)
            sl[v][t] = (t < L) ? __expf(sl[v][t] - m) * inv : 0.f;
    }
    __syncthreads();
    if (tid < TCD) {
        float s = 0.f;
        for (int v = 0; v < TVD; v++) s += sl[v][tid];
        wbar[(long)br * TCD + tid] = s * (1.0f / TVD);
    }
}

__launch_bounds__(256)
__global__ void capftr_kernel(const float* __restrict__ wbar,
                              const float* __restrict__ cap_h,
                              float* __restrict__ out2)
{
    const int idx = blockIdx.x * 256 + threadIdx.x;
    const int h = idx & 511;
    const int br = idx >> 9;
    const int bc = br >> 5;
    float s = 0.f;
#pragma unroll
    for (int t = 0; t < TCD; t++)
        s += wbar[br * TCD + t] * cap_h[(long)(bc * TCD + t) * HD + h];
    out2[idx] = s;
}

// vid_mean from bf16 vid_h
__launch_bounds__(256)
__global__ void vidmean_bf_kernel(const unsigned short* __restrict__ vid_h,
                                  float* __restrict__ out1)
{
    const int idx = blockIdx.x * 256 + threadIdx.x;   // 0..32767
    const int b = idx >> 6;
    const int h8 = (idx & 63) * 8;
    float s[8] = {};
    for (int t = 0; t < TVD; t++) {
        const short8v v = *(const short8v*)(vid_h + ((long)b * TVD + t) * 512 + h8);
#pragma unroll
        for (int j = 0; j < 8; j++) s[j] += b2f((unsigned short)v[j]);
    }
#pragma unroll
    for (int j = 0; j < 8; j++)
        out1[(long)b * 512 + h8 + j] = s[j] * (1.0f / TVD);
}

extern "C" void kernel_launch(void* const* d_in, const int* in_sizes, int n_in,
                              void* d_out, int out_size, void* d_ws, size_t ws_size,
                              hipStream_t stream) {
    const float* video_fc      = (const float*)d_in[0];
    const float* video_caption = (const float*)d_in[1];
    const int*   cap_len       = (const int*)d_in[2];
    const float* W_vemb = (const float*)d_in[3];
    const float* b_vemb = (const float*)d_in[4];
    const float* W_wemb = (const float*)d_in[5];
    const float* b_wemb = (const float*)d_in[6];
    const float* Wih_v  = (const float*)d_in[7];
    const float* Whh_v  = (const float*)d_in[8];
    const float* bih_v  = (const float*)d_in[9];
    const float* bhh_v  = (const float*)d_in[10];
    const float* Wih_c  = (const float*)d_in[11];
    const float* Whh_c  = (const float*)d_in[12];
    const float* bih_c  = (const float*)d_in[13];
    const float* bhh_c  = (const float*)d_in[14];
    const float* W_vid  = (const float*)d_in[15];
    const float* b_vid  = (const float*)d_in[16];
    const float* W_sen  = (const float*)d_in[17];
    const float* b_sen  = (const float*)d_in[18];
    const float* W_att  = (const float*)d_in[19];
    const float* b_att  = (const float*)d_in[20];

    float* out1 = (float*)d_out;            // vid_mean
    float* out2 = out1 + BD * HD;           // cap_ftr_mean

    float* ws = (float*)d_ws;
    size_t off = 0;
    auto alloc = [&](size_t nfloats) {
        float* p = ws + off;
        off += (nfloats + 63) & ~(size_t)63;
        return p;
    };
    unsigned short* vidx_bf = (unsigned short*)alloc((size_t)BD * TVD * VEMBD / 2);
    unsigned short* vidh_bf = (unsigned short*)alloc((size_t)BD * TVD * HD / 2);
    unsigned short* h_bf_a  = (unsigned short*)alloc((size_t)BD * HD / 2);
    unsigned short* h_bf_b  = (unsigned short*)alloc((size_t)BD * HD / 2);
    float* c_st    = alloc((size_t)BD * HD);
    float* v_lin   = alloc((size_t)BD * TVD * AD);
    unsigned short* Wvemb_bf = (unsigned short*)alloc((size_t)VEMBD * FCD / 2);
    unsigned short* Wvid_bf  = (unsigned short*)alloc((size_t)AD * HD / 2);
    unsigned short* Wcat_bf  = (unsigned short*)alloc((size_t)2048 * 1024 / 2);
    float* bsum    = alloc(2048);
    float* cap_x   = alloc((size_t)BCD * TCD * WEMBD);
    float* xg_c    = alloc((size_t)BCD * TCD * 4 * HD);
    float* cap_h   = alloc((size_t)BCD * TCD * HD);
    float* c_lin   = alloc((size_t)BCD * TCD * AD);
    float* wbar    = alloc((size_t)BD * TCD);
    float* cap_ha  = alloc((size_t)BCD * HD);
    float* cap_hb  = alloc((size_t)BCD * HD);
    float* cap_cst = alloc((size_t)BCD * HD);

    hipMemsetAsync(h_bf_a, 0, (size_t)BD * HD * sizeof(unsigned short), stream);
    hipMemsetAsync(c_st, 0, (size_t)BD * HD * sizeof(float), stream);
    hipMemsetAsync(cap_ha, 0, (size_t)BCD * HD * sizeof(float), stream);
    hipMemsetAsync(cap_cst, 0, (size_t)BCD * HD * sizeof(float), stream);

    // weight conversions
    conv_f2b_kernel<<<512, 256, 0, stream>>>(W_vemb, Wvemb_bf, VEMBD * FCD / 4);
    conv_f2b_kernel<<<128, 256, 0, stream>>>(W_vid, Wvid_bf, AD * HD / 4);
    conv_wcat_perm_kernel<<<2048, 256, 0, stream>>>(Wih_v, Whh_v, Wcat_bf);
    conv_bsum_kernel<<<8, 256, 0, stream>>>(bih_v, bhh_v, bsum);

    // caption path (fp32)
    gemm_bias_kernel<<<dim3(WEMBD / 64, (BCD * TCD) / 64), 256, 0, stream>>>(
        video_caption, W_wemb, b_wemb, cap_x, BCD * TCD, WEMBD, GLOVED);
    gemm_bias_kernel<<<dim3((4 * HD) / 64, (BCD * TCD) / 64), 256, 0, stream>>>(
        cap_x, Wih_c, bih_c, xg_c, BCD * TCD, 4 * HD, WEMBD);
    for (int t = 0; t < TCD; t++) {
        const float* hin = (t & 1) ? cap_hb : cap_ha;
        float* hout = (t & 1) ? cap_ha : cap_hb;
        cap_step_kernel<<<32, 256, 0, stream>>>(xg_c, Whh_c, bhh_c, hin, hout, cap_cst, cap_h, t);
    }
    gemm_bias_kernel<<<dim3(AD / 64, (BCD * TCD) / 64), 256, 0, stream>>>(
        cap_h, W_sen, b_sen, c_lin, BCD * TCD, AD, HD);

    // video path (bf16 MFMA)
    mfma_gemm128<1, 1><<<dim3((BD * TVD) / 128, VEMBD / 128), 256, 0, stream>>>(
        video_fc, Wvemb_bf, b_vemb, vidx_bf, BD * TVD, VEMBD, FCD);
    for (int t = 0; t < TVD; t++) {
        const unsigned short* hin = (t & 1) ? h_bf_b : h_bf_a;
        unsigned short* hout = (t & 1) ? h_bf_a : h_bf_b;
        vid_step_mfma<<<dim3(2048 / 64, BD / 64), 256, 0, stream>>>(
            vidx_bf, hin, Wcat_bf, bsum, c_st, hout, vidh_bf, t);
    }
    mfma_gemm128<0, 0><<<dim3((BD * TVD) / 128, AD / 128), 256, 0, stream>>>(
        vidh_bf, Wvid_bf, b_vid, v_lin, BD * TVD, AD, HD);

    // attention + outputs
    attn_kernel<<<BD, 256, 0, stream>>>(v_lin, c_lin, W_att, b_att, cap_len, wbar);
    capftr_kernel<<<(BD * HD) / 256, 256, 0, stream>>>(wbar, cap_h, out2);
    vidmean_bf_kernel<<<(BD * HD / 8) / 256, 256, 0, stream>>>(vidh_bf, out1);
}

// Round 7
// 884.184 us; speedup vs baseline: 2.8589x; 1.1348x over previous
//
#include <hip/hip_runtime.h>
#include <hip/hip_bf16.h>

#define FCD 2048
#define VEMBD 512
#define WEMBD 512
#define HD 512
#define AD 256
#define TVD 32
#define TCD 20
#define BCD 16
#define RPD 32
#define BD 512     // BCD*RPD
#define GLOVED 300

typedef __attribute__((ext_vector_type(8))) short short8v;
typedef __attribute__((ext_vector_type(4))) float f32x4;

__device__ __forceinline__ float sigf(float x) { return 1.0f / (1.0f + __expf(-x)); }
__device__ __forceinline__ float tanhfast(float x) {
    float e = __expf(2.0f * x);
    return 1.0f - 2.0f / (e + 1.0f);
}
__device__ __forceinline__ unsigned short f2bf(float x) {
    union { __hip_bfloat16 h; unsigned short u; } v;
    v.h = __float2bfloat16(x);
    return v.u;
}
__device__ __forceinline__ float b2f(unsigned short u) {
    union { unsigned int i; float f; } v;
    v.i = ((unsigned int)u) << 16;
    return v.f;
}

// ---------------------------------------------------------------------------
// fp32 -> bf16 elementwise convert
// ---------------------------------------------------------------------------
__launch_bounds__(256)
__global__ void conv_f2b_kernel(const float* __restrict__ src,
                                unsigned short* __restrict__ dst, int n4) {
    for (int i = blockIdx.x * 256 + threadIdx.x; i < n4; i += gridDim.x * 256) {
        const float4 v = ((const float4*)src)[i];
        ushort4 o;
        o.x = f2bf(v.x); o.y = f2bf(v.y); o.z = f2bf(v.z); o.w = f2bf(v.w);
        ((ushort4*)dst)[i] = o;
    }
}

// Permuted+concatenated gate weights: Wcat[g'][0:512]=Wih[g], [512:1024]=Whh[g]
// g' = (hc>>4)*64 + q*16 + (hc&15), g = q*512 + hc. bf16 out.
__launch_bounds__(256)
__global__ void conv_wcat_perm_kernel(const float* __restrict__ Wih,
                                      const float* __restrict__ Whh,
                                      unsigned short* __restrict__ Wcat) {
    const int gp = blockIdx.x;
    const int q = (gp >> 4) & 3;
    const int hc = (gp >> 6) * 16 + (gp & 15);
    const long g = (long)(q * 512 + hc);
    for (int k = threadIdx.x; k < 512; k += 256) {
        Wcat[(long)gp * 1024 + k]       = f2bf(Wih[g * 512 + k]);
        Wcat[(long)gp * 1024 + 512 + k] = f2bf(Whh[g * 512 + k]);
    }
}

__launch_bounds__(256)
__global__ void conv_bsum_kernel(const float* __restrict__ bih,
                                 const float* __restrict__ bhh,
                                 float* __restrict__ bsum) {
    const int gp = blockIdx.x * 256 + threadIdx.x;
    if (gp < 2048) {
        const int q = (gp >> 4) & 3;
        const int hc = (gp >> 6) * 16 + (gp & 15);
        const int g = q * 512 + hc;
        bsum[gp] = bih[g] + bhh[g];
    }
}

// ---------------------------------------------------------------------------
// MFMA bf16 GEMM, 128x128 tile, BK=64, register-prefetch staging (next
// chunk's global loads issue before current chunk's MFMAs; LDS write after
// the barrier). Grid: x = m-tiles (fastest), y = n-tiles.
// ---------------------------------------------------------------------------
template<int AF32, int OBF>
__launch_bounds__(256)
__global__ void mfma_gemm128(const void* __restrict__ A,
                             const unsigned short* __restrict__ Bw,
                             const float* __restrict__ bias,
                             void* __restrict__ Cout,
                             int M, int N, int K)
{
    __shared__ unsigned short As[128][72];   // stride 144B = 4 banks mod 32
    __shared__ unsigned short Bs[128][72];
    const int m0 = blockIdx.x * 128;
    const int n0 = blockIdx.y * 128;
    const int tid = threadIdx.x;
    const int lane = tid & 63;
    const int wid = tid >> 6;
    const int wm = (wid >> 1) * 64;
    const int wn = (wid & 1) * 64;
    const int lrow = lane & 15;
    const int lko = (lane >> 4) * 8;
    const int sr = tid >> 1;          // staging row 0..127
    const int sc = (tid & 1) * 32;    // staging col base (32 elems/thread)

    f32x4 acc[4][4] = {};

    const float* Arow_f = (const float*)A + (long)(m0 + sr) * K;
    const unsigned short* Arow_b = (const unsigned short*)A + (long)(m0 + sr) * K;
    const unsigned short* Brow = Bw + (long)(n0 + sr) * K;

    // stage chunk 0
    if (AF32) {
#pragma unroll
        for (int i = 0; i < 8; i++) {
            const float4 v = *(const float4*)(Arow_f + sc + i * 4);
            unsigned short* d = &As[sr][sc + i * 4];
            d[0] = f2bf(v.x); d[1] = f2bf(v.y); d[2] = f2bf(v.z); d[3] = f2bf(v.w);
        }
    } else {
#pragma unroll
        for (int i = 0; i < 4; i++)
            *(short8v*)&As[sr][sc + i * 8] = *(const short8v*)(Arow_b + sc + i * 8);
    }
#pragma unroll
    for (int i = 0; i < 4; i++)
        *(short8v*)&Bs[sr][sc + i * 8] = *(const short8v*)(Brow + sc + i * 8);
    __syncthreads();

    const int nc = K >> 6;
    float4 paf[8];
    short8v pab[4], pb[4];
    for (int c = 0; c < nc; c++) {
        if (c < nc - 1) {
            const int k0 = (c + 1) * 64;
            if (AF32) {
#pragma unroll
                for (int i = 0; i < 8; i++)
                    paf[i] = *(const float4*)(Arow_f + k0 + sc + i * 4);
            } else {
#pragma unroll
                for (int i = 0; i < 4; i++)
                    pab[i] = *(const short8v*)(Arow_b + k0 + sc + i * 8);
            }
#pragma unroll
            for (int i = 0; i < 4; i++)
                pb[i] = *(const short8v*)(Brow + k0 + sc + i * 8);
        }
#pragma unroll
        for (int kk = 0; kk < 2; kk++) {
            short8v a[4], b[4];
#pragma unroll
            for (int mi = 0; mi < 4; mi++)
                a[mi] = *(const short8v*)&As[wm + mi * 16 + lrow][kk * 32 + lko];
#pragma unroll
            for (int ni = 0; ni < 4; ni++)
                b[ni] = *(const short8v*)&Bs[wn + ni * 16 + lrow][kk * 32 + lko];
#pragma unroll
            for (int mi = 0; mi < 4; mi++)
#pragma unroll
                for (int ni = 0; ni < 4; ni++)
                    acc[mi][ni] = __builtin_amdgcn_mfma_f32_16x16x32_bf16(
                        a[mi], b[ni], acc[mi][ni], 0, 0, 0);
        }
        __syncthreads();
        if (c < nc - 1) {
            if (AF32) {
#pragma unroll
                for (int i = 0; i < 8; i++) {
                    unsigned short* d = &As[sr][sc + i * 4];
                    d[0] = f2bf(paf[i].x); d[1] = f2bf(paf[i].y);
                    d[2] = f2bf(paf[i].z); d[3] = f2bf(paf[i].w);
                }
            } else {
#pragma unroll
                for (int i = 0; i < 4; i++)
                    *(short8v*)&As[sr][sc + i * 8] = pab[i];
            }
#pragma unroll
            for (int i = 0; i < 4; i++)
                *(short8v*)&Bs[sr][sc + i * 8] = pb[i];
            __syncthreads();
        }
    }

    const int rbase = (lane >> 4) * 4;
#pragma unroll
    for (int ni = 0; ni < 4; ni++) {
        const int col = n0 + wn + ni * 16 + lrow;
        const float bv = bias[col];
#pragma unroll
        for (int mi = 0; mi < 4; mi++) {
#pragma unroll
            for (int j = 0; j < 4; j++) {
                const long row = m0 + wm + mi * 16 + rbase + j;
                const float val = acc[mi][ni][j] + bv;
                if (OBF) ((unsigned short*)Cout)[row * N + col] = f2bf(val);
                else     ((float*)Cout)[row * N + col] = val;
            }
        }
    }
}

// ---------------------------------------------------------------------------
// Fused LSTM step kernel, 512 threads.
// Blocks 0..255: video step. 64 batch x 64 g' tile. Two 4-wave groups
//   K-split: group 0 -> k 0..511 (vx@Wih), group 1 -> k 512..1023 (h@Whh);
//   each group 4 chunks of 128 with register-prefetch; acc combined via LDS;
//   group 0 does the cell update (same math/order as before).
// Blocks 256..287 (only launched when t<TC): caption LSTM step (fp32),
//   identical math to the old cap_step_kernel, restaged for 512 threads.
// ---------------------------------------------------------------------------
__launch_bounds__(512)
__global__ void step_fused(const unsigned short* __restrict__ vx,   // [B*TV][512] bf16
                           const unsigned short* __restrict__ h_in, // [B][512] bf16
                           unsigned short* __restrict__ h_out,      // [B][512] bf16
                           const unsigned short* __restrict__ Wcat, // [2048][1024] bf16
                           const float* __restrict__ bsum,          // [2048]
                           float* __restrict__ c_state,             // [B][512] f32
                           unsigned short* __restrict__ vid_h,      // [B*TV][512] bf16
                           int t,
                           const float* __restrict__ xg,            // cap: [BC*TC][2048]
                           const float* __restrict__ Whh_c,         // cap: [2048][512] f32
                           const float* __restrict__ bhh_c,         // cap: [2048]
                           const float* __restrict__ hc_in,         // cap: [BC][512] f32
                           float* __restrict__ hc_out,              // cap: [BC][512] f32
                           float* __restrict__ cap_cst,             // cap: [BC][512] f32
                           float* __restrict__ cap_h)               // cap: [BC*TC][512] f32
{
    __shared__ __align__(16) unsigned char smem[69632];
    const int bx = blockIdx.x;
    const int tid = threadIdx.x;

    if (bx >= 256) {
        // ---------------- caption step ----------------
        const int h0 = (bx - 256) * 16;
        float* Wsc = (float*)smem;              // [64][68]
        float* Hshc = (float*)(smem + 17408);   // [16][68]
        const int lrow = tid >> 3;      // 0..63
        const int lq8 = tid & 7;
        const int tx = tid & 15;
        const int ty = (tid >> 4) & 15;
        float acc4[4] = {};

        for (int k0 = 0; k0 < 512; k0 += 64) {
            {
                const int q = lrow >> 4;
                const int hcc = lrow & 15;
                const float* src = Whh_c + (long)(q * 512 + h0 + hcc) * 512 + k0 + lq8 * 8;
                const int col = hcc * 4 + q;
#pragma unroll
                for (int j = 0; j < 2; j++) {
                    const float4 v = *(const float4*)(src + j * 4);
                    Wsc[(lq8 * 8 + j * 4 + 0) * 68 + col] = v.x;
                    Wsc[(lq8 * 8 + j * 4 + 1) * 68 + col] = v.y;
                    Wsc[(lq8 * 8 + j * 4 + 2) * 68 + col] = v.z;
                    Wsc[(lq8 * 8 + j * 4 + 3) * 68 + col] = v.w;
                }
            }
            if (tid < 256) {
                const int lb = tid >> 4;
                const int lk4 = (tid & 15) * 4;
                *(float4*)&Hshc[lb * 68 + lk4] = *(const float4*)(hc_in + (long)lb * 512 + k0 + lk4);
            }
            __syncthreads();
            if (tid < 256) {
#pragma unroll
                for (int kq = 0; kq < 16; kq++) {
                    const float4 h4 = *(const float4*)&Hshc[ty * 68 + kq * 4];
                    const float4 w0 = *(const float4*)&Wsc[(kq * 4 + 0) * 68 + tx * 4];
                    const float4 w1 = *(const float4*)&Wsc[(kq * 4 + 1) * 68 + tx * 4];
                    const float4 w2 = *(const float4*)&Wsc[(kq * 4 + 2) * 68 + tx * 4];
                    const float4 w3 = *(const float4*)&Wsc[(kq * 4 + 3) * 68 + tx * 4];
                    acc4[0] += h4.x * w0.x + h4.y * w1.x + h4.z * w2.x + h4.w * w3.x;
                    acc4[1] += h4.x * w0.y + h4.y * w1.y + h4.z * w2.y + h4.w * w3.y;
                    acc4[2] += h4.x * w0.z + h4.y * w1.z + h4.z * w2.z + h4.w * w3.z;
                    acc4[3] += h4.x * w0.w + h4.y * w1.w + h4.z * w2.w + h4.w * w3.w;
                }
            }
            __syncthreads();
        }
        if (tid < 256) {
            const int hc = h0 + tx;
            const long xrow = (long)(ty * TCD + t) * 2048;
            const float gi = acc4[0] + xg[xrow + hc]        + bhh_c[hc];
            const float gf = acc4[1] + xg[xrow + 512 + hc]  + bhh_c[512 + hc];
            const float gg = acc4[2] + xg[xrow + 1024 + hc] + bhh_c[1024 + hc];
            const float go = acc4[3] + xg[xrow + 1536 + hc] + bhh_c[1536 + hc];
            const float c_old = cap_cst[(long)ty * 512 + hc];
            const float ii = sigf(gi), ff = sigf(gf), g2 = tanhfast(gg), oo = sigf(go);
            const float c = ff * c_old + ii * g2;
            const float h = oo * tanhfast(c);
            cap_cst[(long)ty * 512 + hc] = c;
            hc_out[(long)ty * 512 + hc] = h;
            cap_h[(long)(ty * TCD + t) * 512 + hc] = h;
        }
        return;
    }

    // ---------------- video step ----------------
    const int n0 = (bx & 31) * 64;   // g' base
    const int b0 = (bx >> 5) * 64;   // batch base
    const int lane = tid & 63;
    const int wl = (tid >> 6) & 3;   // wave within group
    const int g = tid >> 8;          // k-split group
    const int lrow = lane & 15;
    const int lko = (lane >> 4) * 8;
    const int sr = tid >> 3;         // staging row 0..63
    const int sc = (tid & 7) * 16;   // staging col base (16 elems/thread/buffer)

    unsigned short* As0 = (unsigned short*)smem;              // [64][136]
    unsigned short* Ws0 = (unsigned short*)(smem + 17408);
    unsigned short* As1 = (unsigned short*)(smem + 34816);
    unsigned short* Ws1 = (unsigned short*)(smem + 52224);
    unsigned short* Asg = (unsigned short*)(smem + g * 34816);
    unsigned short* Wsg = Asg + 17408 / 2;

    const unsigned short* arow_vx = vx + ((long)(b0 + sr) * TVD + t) * 512;
    const unsigned short* arow_h  = h_in + (long)(b0 + sr) * 512;
    const unsigned short* wrow    = Wcat + (long)(n0 + sr) * 1024;

    f32x4 acc[4] = {};

    // stage phase 0: group0 chunk0 (vx k0..127), group1 chunk4 (h k0..127)
#pragma unroll
    for (int i = 0; i < 2; i++) {
        *(short8v*)&As0[sr * 136 + sc + i * 8] = *(const short8v*)(arow_vx + sc + i * 8);
        *(short8v*)&Ws0[sr * 136 + sc + i * 8] = *(const short8v*)(wrow + sc + i * 8);
        *(short8v*)&As1[sr * 136 + sc + i * 8] = *(const short8v*)(arow_h + sc + i * 8);
        *(short8v*)&Ws1[sr * 136 + sc + i * 8] = *(const short8v*)(wrow + 512 + sc + i * 8);
    }
    __syncthreads();

    short8v pa0[2], pw0[2], pa1[2], pw1[2];
    for (int p = 0; p < 4; p++) {
        if (p < 3) {
            const int k0 = (p + 1) * 128;
#pragma unroll
            for (int i = 0; i < 2; i++) {
                pa0[i] = *(const short8v*)(arow_vx + k0 + sc + i * 8);
                pw0[i] = *(const short8v*)(wrow + k0 + sc + i * 8);
                pa1[i] = *(const short8v*)(arow_h + k0 + sc + i * 8);
                pw1[i] = *(const short8v*)(wrow + 512 + k0 + sc + i * 8);
            }
        }
#pragma unroll
        for (int kk = 0; kk < 4; kk++) {
            const short8v a = *(const short8v*)&Asg[(wl * 16 + lrow) * 136 + kk * 32 + lko];
#pragma unroll
            for (int ni = 0; ni < 4; ni++) {
                const short8v b = *(const short8v*)&Wsg[(ni * 16 + lrow) * 136 + kk * 32 + lko];
                acc[ni] = __builtin_amdgcn_mfma_f32_16x16x32_bf16(a, b, acc[ni], 0, 0, 0);
            }
        }
        __syncthreads();
        if (p < 3) {
#pragma unroll
            for (int i = 0; i < 2; i++) {
                *(short8v*)&As0[sr * 136 + sc + i * 8] = pa0[i];
                *(short8v*)&Ws0[sr * 136 + sc + i * 8] = pw0[i];
                *(short8v*)&As1[sr * 136 + sc + i * 8] = pa1[i];
                *(short8v*)&Ws1[sr * 136 + sc + i * 8] = pw1[i];
            }
            __syncthreads();
        }
    }

    // combine group 1 acc into group 0 via LDS ([16][256] f32, stride-1)
    float* red = (float*)(smem + 34816);
    const int flat = wl * 64 + lane;    // 0..255 within group
    if (g == 1) {
#pragma unroll
        for (int ni = 0; ni < 4; ni++)
#pragma unroll
            for (int j = 0; j < 4; j++)
                red[(ni * 4 + j) * 256 + flat] = acc[ni][j];
    }
    __syncthreads();
    if (g == 0) {
        const int hc = (n0 >> 2) + lrow;
        const int rbase = (lane >> 4) * 4;
        const float bs0 = bsum[n0 + lrow];
        const float bs1 = bsum[n0 + 16 + lrow];
        const float bs2 = bsum[n0 + 32 + lrow];
        const float bs3 = bsum[n0 + 48 + lrow];
#pragma unroll
        for (int j = 0; j < 4; j++) {
            const long b = b0 + wl * 16 + rbase + j;
            const float gi = acc[0][j] + red[(0 * 4 + j) * 256 + flat] + bs0;
            const float gf = acc[1][j] + red[(1 * 4 + j) * 256 + flat] + bs1;
            const float gg = acc[2][j] + red[(2 * 4 + j) * 256 + flat] + bs2;
            const float go = acc[3][j] + red[(3 * 4 + j) * 256 + flat] + bs3;
            const float c_old = c_state[b * 512 + hc];
            const float ii = sigf(gi), ff = sigf(gf), g2 = tanhfast(gg), oo = sigf(go);
            const float cn = ff * c_old + ii * g2;
            const float h = oo * tanhfast(cn);
            c_state[b * 512 + hc] = cn;
            h_out[b * 512 + hc] = f2bf(h);
            vid_h[(b * TVD + t) * 512 + hc] = f2bf(h);
        }
    }
}

// ---------------------------------------------------------------------------
// Generic fp32 tiled GEMM (cap front path + c_lin)
// ---------------------------------------------------------------------------
__launch_bounds__(256)
__global__ void gemm_bias_kernel(const float* __restrict__ A,
                                 const float* __restrict__ Bw,
                                 const float* __restrict__ bias,
                                 float* __restrict__ C,
                                 int M, int N, int K) {
    __shared__ float As[16][68];
    __shared__ float Bs[16][68];
    const int n0 = blockIdx.x * 64;
    const int m0 = blockIdx.y * 64;
    const int tid = threadIdx.x;
    const int tx = tid & 15;
    const int ty = tid >> 4;
    const int lrow = tid >> 2;
    const int lk4 = (tid & 3) * 4;

    float acc[4][4] = {};

    for (int k0 = 0; k0 < K; k0 += 16) {
        {
            const float* src = A + (long)(m0 + lrow) * K + k0 + lk4;
            float4 v;
            if (k0 + 16 <= K) v = *(const float4*)src;
            else {
                v.x = (k0 + lk4 + 0 < K) ? src[0] : 0.f;
                v.y = (k0 + lk4 + 1 < K) ? src[1] : 0.f;
                v.z = (k0 + lk4 + 2 < K) ? src[2] : 0.f;
                v.w = (k0 + lk4 + 3 < K) ? src[3] : 0.f;
            }
            As[lk4 + 0][lrow] = v.x; As[lk4 + 1][lrow] = v.y;
            As[lk4 + 2][lrow] = v.z; As[lk4 + 3][lrow] = v.w;
        }
        {
            const float* src = Bw + (long)(n0 + lrow) * K + k0 + lk4;
            float4 v;
            if (k0 + 16 <= K) v = *(const float4*)src;
            else {
                v.x = (k0 + lk4 + 0 < K) ? src[0] : 0.f;
                v.y = (k0 + lk4 + 1 < K) ? src[1] : 0.f;
                v.z = (k0 + lk4 + 2 < K) ? src[2] : 0.f;
                v.w = (k0 + lk4 + 3 < K) ? src[3] : 0.f;
            }
            Bs[lk4 + 0][lrow] = v.x; Bs[lk4 + 1][lrow] = v.y;
            Bs[lk4 + 2][lrow] = v.z; Bs[lk4 + 3][lrow] = v.w;
        }
        __syncthreads();
#pragma unroll
        for (int kk = 0; kk < 16; kk++) {
            const float4 av = *(const float4*)&As[kk][ty * 4];
            const float4 bv = *(const float4*)&Bs[kk][tx * 4];
            acc[0][0] += av.x * bv.x; acc[0][1] += av.x * bv.y; acc[0][2] += av.x * bv.z; acc[0][3] += av.x * bv.w;
            acc[1][0] += av.y * bv.x; acc[1][1] += av.y * bv.y; acc[1][2] += av.y * bv.z; acc[1][3] += av.y * bv.w;
            acc[2][0] += av.z * bv.x; acc[2][1] += av.z * bv.y; acc[2][2] += av.z * bv.z; acc[2][3] += av.z * bv.w;
            acc[3][0] += av.w * bv.x; acc[3][1] += av.w * bv.y; acc[3][2] += av.w * bv.z; acc[3][3] += av.w * bv.w;
        }
        __syncthreads();
    }

    const float b0v = bias[n0 + tx * 4 + 0];
    const float b1v = bias[n0 + tx * 4 + 1];
    const float b2v = bias[n0 + tx * 4 + 2];
    const float b3v = bias[n0 + tx * 4 + 3];
#pragma unroll
    for (int i = 0; i < 4; i++) {
        float* dst = C + (long)(m0 + ty * 4 + i) * N + n0 + tx * 4;
        dst[0] = acc[i][0] + b0v;
        dst[1] = acc[i][1] + b1v;
        dst[2] = acc[i][2] + b2v;
        dst[3] = acc[i][3] + b3v;
    }
}

// ---------------------------------------------------------------------------
// Attention: one block per (bc, rp); scores -> masked softmax -> wbar mean_v.
// ---------------------------------------------------------------------------
__launch_bounds__(256)
__global__ void attn_kernel(const float* __restrict__ v_lin,
                            const float* __restrict__ c_lin,
                            const float* __restrict__ W_att,
                            const float* __restrict__ b_att,
                            const int* __restrict__ cap_len,
                            float* __restrict__ wbar)
{
    const int br = blockIdx.x;
    const int bc = br >> 5;
    const int tid = threadIdx.x;
    const int lane = tid & 63;
    const int wv = tid >> 6;
    __shared__ float cl[TCD][AD];
    __shared__ float vl[AD];
    __shared__ float sl[TVD][TCD];

    for (int tt = 0; tt < TCD; tt++)
        cl[tt][tid] = c_lin[(long)(bc * TCD + tt) * AD + tid];
    const float wa0 = W_att[lane];
    const float wa1 = W_att[64 + lane];
    const float wa2 = W_att[128 + lane];
    const float wa3 = W_att[192 + lane];
    const float batt = b_att[0];
    __syncthreads();

    for (int v = 0; v < TVD; v++) {
        vl[tid] = v_lin[((long)br * TVD + v) * AD + tid];
        __syncthreads();
        const float v0 = vl[lane], v1 = vl[64 + lane], v2 = vl[128 + lane], v3 = vl[192 + lane];
#pragma unroll
        for (int dt = 0; dt < 5; dt++) {
            const int t = wv * 5 + dt;
            float s = tanhfast(v0 + cl[t][lane]) * wa0
                    + tanhfast(v1 + cl[t][64 + lane]) * wa1
                    + tanhfast(v2 + cl[t][128 + lane]) * wa2
                    + tanhfast(v3 + cl[t][192 + lane]) * wa3;
            for (int off = 32; off > 0; off >>= 1) s += __shfl_down(s, off, 64);
            if (lane == 0) sl[v][t] = s + batt;
        }
        __syncthreads();
    }

    int L = cap_len[bc];
    if (L < 1) L = 1;
    if (tid < TVD) {
        const int v = tid;
        float m = -1e30f;
        for (int t = 0; t < TCD; t++)
            if (t < L) m = fmaxf(m, sl[v][t]);
        float sum = 0.f;
        for (int t = 0; t < TCD; t++)
            if (t < L) sum += __expf(sl[v][t] - m);
        const float inv = 1.f / sum;
        for (int t = 0; t < TCD; t++)
            sl[v][t] = (t < L) ? __expf(sl[v][t] - m) * inv : 0.f;
    }
    __syncthreads();
    if (tid < TCD) {
        float s = 0.f;
        for (int v = 0; v < TVD; v++) s += sl[v][tid];
        wbar[(long)br * TCD + tid] = s * (1.0f / TVD);
    }
}

__launch_bounds__(256)
__global__ void capftr_kernel(const float* __restrict__ wbar,
                              const float* __restrict__ cap_h,
                              float* __restrict__ out2)
{
    const int idx = blockIdx.x * 256 + threadIdx.x;
    const int h = idx & 511;
    const int br = idx >> 9;
    const int bc = br >> 5;
    float s = 0.f;
#pragma unroll
    for (int t = 0; t < TCD; t++)
        s += wbar[br * TCD + t] * cap_h[(long)(bc * TCD + t) * HD + h];
    out2[idx] = s;
}

// vid_mean from bf16 vid_h
__launch_bounds__(256)
__global__ void vidmean_bf_kernel(const unsigned short* __restrict__ vid_h,
                                  float* __restrict__ out1)
{
    const int idx = blockIdx.x * 256 + threadIdx.x;   // 0..32767
    const int b = idx >> 6;
    const int h8 = (idx & 63) * 8;
    float s[8] = {};
    for (int t = 0; t < TVD; t++) {
        const short8v v = *(const short8v*)(vid_h + ((long)b * TVD + t) * 512 + h8);
#pragma unroll
        for (int j = 0; j < 8; j++) s[j] += b2f((unsigned short)v[j]);
    }
#pragma unroll
    for (int j = 0; j < 8; j++)
        out1[(long)b * 512 + h8 + j] = s[j] * (1.0f / TVD);
}

extern "C" void kernel_launch(void* const* d_in, const int* in_sizes, int n_in,
                              void* d_out, int out_size, void* d_ws, size_t ws_size,
                              hipStream_t stream) {
    const float* video_fc      = (const float*)d_in[0];
    const float* video_caption = (const float*)d_in[1];
    const int*   cap_len       = (const int*)d_in[2];
    const float* W_vemb = (const float*)d_in[3];
    const float* b_vemb = (const float*)d_in[4];
    const float* W_wemb = (const float*)d_in[5];
    const float* b_wemb = (const float*)d_in[6];
    const float* Wih_v  = (const float*)d_in[7];
    const float* Whh_v  = (const float*)d_in[8];
    const float* bih_v  = (const float*)d_in[9];
    const float* bhh_v  = (const float*)d_in[10];
    const float* Wih_c  = (const float*)d_in[11];
    const float* Whh_c  = (const float*)d_in[12];
    const float* bih_c  = (const float*)d_in[13];
    const float* bhh_c  = (const float*)d_in[14];
    const float* W_vid  = (const float*)d_in[15];
    const float* b_vid  = (const float*)d_in[16];
    const float* W_sen  = (const float*)d_in[17];
    const float* b_sen  = (const float*)d_in[18];
    const float* W_att  = (const float*)d_in[19];
    const float* b_att  = (const float*)d_in[20];

    float* out1 = (float*)d_out;            // vid_mean
    float* out2 = out1 + BD * HD;           // cap_ftr_mean

    float* ws = (float*)d_ws;
    size_t off = 0;
    auto alloc = [&](size_t nfloats) {
        float* p = ws + off;
        off += (nfloats + 63) & ~(size_t)63;
        return p;
    };
    unsigned short* vidx_bf = (unsigned short*)alloc((size_t)BD * TVD * VEMBD / 2);
    unsigned short* vidh_bf = (unsigned short*)alloc((size_t)BD * TVD * HD / 2);
    unsigned short* h_bf_a  = (unsigned short*)alloc((size_t)BD * HD / 2);
    unsigned short* h_bf_b  = (unsigned short*)alloc((size_t)BD * HD / 2);
    float* c_st    = alloc((size_t)BD * HD);
    float* v_lin   = alloc((size_t)BD * TVD * AD);
    unsigned short* Wvemb_bf = (unsigned short*)alloc((size_t)VEMBD * FCD / 2);
    unsigned short* Wvid_bf  = (unsigned short*)alloc((size_t)AD * HD / 2);
    unsigned short* Wcat_bf  = (unsigned short*)alloc((size_t)2048 * 1024 / 2);
    float* bsum    = alloc(2048);
    float* cap_x   = alloc((size_t)BCD * TCD * WEMBD);
    float* xg_c    = alloc((size_t)BCD * TCD * 4 * HD);
    float* cap_h   = alloc((size_t)BCD * TCD * HD);
    float* c_lin   = alloc((size_t)BCD * TCD * AD);
    float* wbar    = alloc((size_t)BD * TCD);
    float* cap_ha  = alloc((size_t)BCD * HD);
    float* cap_hb  = alloc((size_t)BCD * HD);
    float* cap_cst = alloc((size_t)BCD * HD);

    hipMemsetAsync(h_bf_a, 0, (size_t)BD * HD * sizeof(unsigned short), stream);
    hipMemsetAsync(c_st, 0, (size_t)BD * HD * sizeof(float), stream);
    hipMemsetAsync(cap_ha, 0, (size_t)BCD * HD * sizeof(float), stream);
    hipMemsetAsync(cap_cst, 0, (size_t)BCD * HD * sizeof(float), stream);

    // weight conversions
    conv_f2b_kernel<<<512, 256, 0, stream>>>(W_vemb, Wvemb_bf, VEMBD * FCD / 4);
    conv_f2b_kernel<<<128, 256, 0, stream>>>(W_vid, Wvid_bf, AD * HD / 4);
    conv_wcat_perm_kernel<<<2048, 256, 0, stream>>>(Wih_v, Whh_v, Wcat_bf);
    conv_bsum_kernel<<<8, 256, 0, stream>>>(bih_v, bhh_v, bsum);

    // caption front path (fp32)
    gemm_bias_kernel<<<dim3(WEMBD / 64, (BCD * TCD) / 64), 256, 0, stream>>>(
        video_caption, W_wemb, b_wemb, cap_x, BCD * TCD, WEMBD, GLOVED);
    gemm_bias_kernel<<<dim3((4 * HD) / 64, (BCD * TCD) / 64), 256, 0, stream>>>(
        cap_x, Wih_c, bih_c, xg_c, BCD * TCD, 4 * HD, WEMBD);

    // vid_x GEMM (bf16 MFMA, m-fastest grid)
    mfma_gemm128<1, 1><<<dim3((BD * TVD) / 128, VEMBD / 128), 256, 0, stream>>>(
        video_fc, Wvemb_bf, b_vemb, vidx_bf, BD * TVD, VEMBD, FCD);

    // fused LSTM steps: vid (blocks 0..255) + cap (blocks 256..287, t<20)
    for (int t = 0; t < TVD; t++) {
        const unsigned short* hin = (t & 1) ? h_bf_b : h_bf_a;
        unsigned short* hout = (t & 1) ? h_bf_a : h_bf_b;
        const float* chin = (t & 1) ? cap_hb : cap_ha;
        float* chout = (t & 1) ? cap_ha : cap_hb;
        const int nblk = (t < TCD) ? 288 : 256;
        step_fused<<<nblk, 512, 0, stream>>>(
            vidx_bf, hin, hout, Wcat_bf, bsum, c_st, vidh_bf, t,
            xg_c, Whh_c, bhh_c, chin, chout, cap_cst, cap_h);
    }

    // post GEMMs
    gemm_bias_kernel<<<dim3(AD / 64, (BCD * TCD) / 64), 256, 0, stream>>>(
        cap_h, W_sen, b_sen, c_lin, BCD * TCD, AD, HD);
    mfma_gemm128<0, 0><<<dim3((BD * TVD) / 128, AD / 128), 256, 0, stream>>>(
        vidh_bf, Wvid_bf, b_vid, v_lin, BD * TVD, AD, HD);

    // attention + outputs
    attn_kernel<<<BD, 256, 0, stream>>>(v_lin, c_lin, W_att, b_att, cap_len, wbar);
    capftr_kernel<<<(BD * HD) / 256, 256, 0, stream>>>(wbar, cap_h, out2);
    vidmean_bf_kernel<<<(BD * HD / 8) / 256, 256, 0, stream>>>(vidh_bf, out1);
}

// Round 8
// 847.548 us; speedup vs baseline: 2.9825x; 1.0432x over previous
//
#include <hip/hip_runtime.h>
#include <hip/hip_bf16.h>

#define FCD 2048
#define VEMBD 512
#define WEMBD 512
#define HD 512
#define AD 256
#define TVD 32
#define TCD 20
#define BCD 16
#define RPD 32
#define BD 512     // BCD*RPD
#define GLOVED 300

typedef __attribute__((ext_vector_type(8))) short short8v;
typedef __attribute__((ext_vector_type(4))) float f32x4;

__device__ __forceinline__ float sigf(float x) { return 1.0f / (1.0f + __expf(-x)); }
__device__ __forceinline__ float tanhfast(float x) {
    float e = __expf(2.0f * x);
    return 1.0f - 2.0f / (e + 1.0f);
}
__device__ __forceinline__ unsigned short f2bf(float x) {
    union { __hip_bfloat16 h; unsigned short u; } v;
    v.h = __float2bfloat16(x);
    return v.u;
}
__device__ __forceinline__ float b2f(unsigned short u) {
    union { unsigned int i; float f; } v;
    v.i = ((unsigned int)u) << 16;
    return v.f;
}

// ---------------------------------------------------------------------------
// fp32 -> bf16 elementwise convert
// ---------------------------------------------------------------------------
__launch_bounds__(256)
__global__ void conv_f2b_kernel(const float* __restrict__ src,
                                unsigned short* __restrict__ dst, int n4) {
    for (int i = blockIdx.x * 256 + threadIdx.x; i < n4; i += gridDim.x * 256) {
        const float4 v = ((const float4*)src)[i];
        ushort4 o;
        o.x = f2bf(v.x); o.y = f2bf(v.y); o.z = f2bf(v.z); o.w = f2bf(v.w);
        ((ushort4*)dst)[i] = o;
    }
}

// Permuted+concatenated gate weights: Wcat[g'][0:512]=Wih[g], [512:1024]=Whh[g]
// g' = (hc>>4)*64 + q*16 + (hc&15), g = q*512 + hc. bf16 out.
__launch_bounds__(256)
__global__ void conv_wcat_perm_kernel(const float* __restrict__ Wih,
                                      const float* __restrict__ Whh,
                                      unsigned short* __restrict__ Wcat) {
    const int gp = blockIdx.x;
    const int q = (gp >> 4) & 3;
    const int hc = (gp >> 6) * 16 + (gp & 15);
    const long g = (long)(q * 512 + hc);
    for (int k = threadIdx.x; k < 512; k += 256) {
        Wcat[(long)gp * 1024 + k]       = f2bf(Wih[g * 512 + k]);
        Wcat[(long)gp * 1024 + 512 + k] = f2bf(Whh[g * 512 + k]);
    }
}

__launch_bounds__(256)
__global__ void conv_bsum_kernel(const float* __restrict__ bih,
                                 const float* __restrict__ bhh,
                                 float* __restrict__ bsum) {
    const int gp = blockIdx.x * 256 + threadIdx.x;
    if (gp < 2048) {
        const int q = (gp >> 4) & 3;
        const int hc = (gp >> 6) * 16 + (gp & 15);
        const int g = q * 512 + hc;
        bsum[gp] = bih[g] + bhh[g];
    }
}

// ---------------------------------------------------------------------------
// MFMA bf16 GEMM, 128x128 tile, BK=64, register-prefetch staging.
// Grid: x = m-tiles (fastest), y = n-tiles.
// ---------------------------------------------------------------------------
template<int AF32, int OBF>
__launch_bounds__(256)
__global__ void mfma_gemm128(const void* __restrict__ A,
                             const unsigned short* __restrict__ Bw,
                             const float* __restrict__ bias,
                             void* __restrict__ Cout,
                             int M, int N, int K)
{
    __shared__ unsigned short As[128][72];
    __shared__ unsigned short Bs[128][72];
    const int m0 = blockIdx.x * 128;
    const int n0 = blockIdx.y * 128;
    const int tid = threadIdx.x;
    const int lane = tid & 63;
    const int wid = tid >> 6;
    const int wm = (wid >> 1) * 64;
    const int wn = (wid & 1) * 64;
    const int lrow = lane & 15;
    const int lko = (lane >> 4) * 8;
    const int sr = tid >> 1;
    const int sc = (tid & 1) * 32;

    f32x4 acc[4][4] = {};

    const float* Arow_f = (const float*)A + (long)(m0 + sr) * K;
    const unsigned short* Arow_b = (const unsigned short*)A + (long)(m0 + sr) * K;
    const unsigned short* Brow = Bw + (long)(n0 + sr) * K;

    if (AF32) {
#pragma unroll
        for (int i = 0; i < 8; i++) {
            const float4 v = *(const float4*)(Arow_f + sc + i * 4);
            unsigned short* d = &As[sr][sc + i * 4];
            d[0] = f2bf(v.x); d[1] = f2bf(v.y); d[2] = f2bf(v.z); d[3] = f2bf(v.w);
        }
    } else {
#pragma unroll
        for (int i = 0; i < 4; i++)
            *(short8v*)&As[sr][sc + i * 8] = *(const short8v*)(Arow_b + sc + i * 8);
    }
#pragma unroll
    for (int i = 0; i < 4; i++)
        *(short8v*)&Bs[sr][sc + i * 8] = *(const short8v*)(Brow + sc + i * 8);
    __syncthreads();

    const int nc = K >> 6;
    float4 paf[8];
    short8v pab[4], pb[4];
    for (int c = 0; c < nc; c++) {
        if (c < nc - 1) {
            const int k0 = (c + 1) * 64;
            if (AF32) {
#pragma unroll
                for (int i = 0; i < 8; i++)
                    paf[i] = *(const float4*)(Arow_f + k0 + sc + i * 4);
            } else {
#pragma unroll
                for (int i = 0; i < 4; i++)
                    pab[i] = *(const short8v*)(Arow_b + k0 + sc + i * 8);
            }
#pragma unroll
            for (int i = 0; i < 4; i++)
                pb[i] = *(const short8v*)(Brow + k0 + sc + i * 8);
        }
#pragma unroll
        for (int kk = 0; kk < 2; kk++) {
            short8v a[4], b[4];
#pragma unroll
            for (int mi = 0; mi < 4; mi++)
                a[mi] = *(const short8v*)&As[wm + mi * 16 + lrow][kk * 32 + lko];
#pragma unroll
            for (int ni = 0; ni < 4; ni++)
                b[ni] = *(const short8v*)&Bs[wn + ni * 16 + lrow][kk * 32 + lko];
#pragma unroll
            for (int mi = 0; mi < 4; mi++)
#pragma unroll
                for (int ni = 0; ni < 4; ni++)
                    acc[mi][ni] = __builtin_amdgcn_mfma_f32_16x16x32_bf16(
                        a[mi], b[ni], acc[mi][ni], 0, 0, 0);
        }
        __syncthreads();
        if (c < nc - 1) {
            if (AF32) {
#pragma unroll
                for (int i = 0; i < 8; i++) {
                    unsigned short* d = &As[sr][sc + i * 4];
                    d[0] = f2bf(paf[i].x); d[1] = f2bf(paf[i].y);
                    d[2] = f2bf(paf[i].z); d[3] = f2bf(paf[i].w);
                }
            } else {
#pragma unroll
                for (int i = 0; i < 4; i++)
                    *(short8v*)&As[sr][sc + i * 8] = pab[i];
            }
#pragma unroll
            for (int i = 0; i < 4; i++)
                *(short8v*)&Bs[sr][sc + i * 8] = pb[i];
            __syncthreads();
        }
    }

    const int rbase = (lane >> 4) * 4;
#pragma unroll
    for (int ni = 0; ni < 4; ni++) {
        const int col = n0 + wn + ni * 16 + lrow;
        const float bv = bias[col];
#pragma unroll
        for (int mi = 0; mi < 4; mi++) {
#pragma unroll
            for (int j = 0; j < 4; j++) {
                const long row = m0 + wm + mi * 16 + rbase + j;
                const float val = acc[mi][ni][j] + bv;
                if (OBF) ((unsigned short*)Cout)[row * N + col] = f2bf(val);
                else     ((float*)Cout)[row * N + col] = val;
            }
        }
    }
}

// ---------------------------------------------------------------------------
// Fused LSTM step, 256 threads, 26.1 KB LDS, 2 blocks/CU (launch_bounds(256,2)).
// Blocks 0..511: vid step, tile = 32 batch x 64 g'. 4 waves: wave w computes
//   gate-pair nq=w>>1 (q = 2nq+{0,1}) for batch-half bi=w&1. K=1024, 8 chunks
//   of 128, 1-deep register prefetch. Waves 2,3 hand q2,q3 to waves 0,1 via a
//   4 KB LDS exchange; waves 0,1 do the cell update (k-order == R4: absmax-
//   stable). Blocks 512..543 (t<TC): caption fp32 step (R6 body, proven).
// ---------------------------------------------------------------------------
__launch_bounds__(256, 2)
__global__ void step_fused(const unsigned short* __restrict__ vx,   // [B*TV][512] bf16
                           const unsigned short* __restrict__ h_in, // [B][512] bf16
                           unsigned short* __restrict__ h_out,      // [B][512] bf16
                           const unsigned short* __restrict__ Wcat, // [2048][1024] bf16
                           const float* __restrict__ bsum,          // [2048]
                           float* __restrict__ c_state,             // [B][512] f32
                           unsigned short* __restrict__ vid_h,      // [B*TV][512] bf16
                           int t,
                           const float* __restrict__ xg,            // cap
                           const float* __restrict__ Whh_c,
                           const float* __restrict__ bhh_c,
                           const float* __restrict__ hc_in,
                           float* __restrict__ hc_out,
                           float* __restrict__ cap_cst,
                           float* __restrict__ cap_h)
{
    __shared__ __align__(16) unsigned char smem[26112];
    const int bx = blockIdx.x;
    const int tid = threadIdx.x;

    if (bx >= 512) {
        // ---------------- caption step (fp32, 256 threads) ----------------
        const int h0 = (bx - 512) * 16;
        float* Wsc = (float*)smem;              // [64][68]
        float* Hshc = (float*)(smem + 17408);   // [16][68]
        const int tx = tid & 15;
        const int ty = tid >> 4;
        const int lrow2 = tid >> 2;
        const int lq = tid & 3;
        float acc4[4] = {};

        for (int k0 = 0; k0 < 512; k0 += 64) {
            {
                const int q = lrow2 >> 4;
                const int hcc = lrow2 & 15;
                const float* src = Whh_c + (long)(q * 512 + h0 + hcc) * 512 + k0 + lq * 16;
                const int col = hcc * 4 + q;
#pragma unroll
                for (int j = 0; j < 4; j++) {
                    const float4 v = *(const float4*)(src + j * 4);
                    Wsc[(lq * 16 + j * 4 + 0) * 68 + col] = v.x;
                    Wsc[(lq * 16 + j * 4 + 1) * 68 + col] = v.y;
                    Wsc[(lq * 16 + j * 4 + 2) * 68 + col] = v.z;
                    Wsc[(lq * 16 + j * 4 + 3) * 68 + col] = v.w;
                }
            }
            {
                const int lb = tid >> 4;
                const int lk4 = (tid & 15) * 4;
                *(float4*)&Hshc[lb * 68 + lk4] = *(const float4*)(hc_in + (long)lb * 512 + k0 + lk4);
            }
            __syncthreads();
#pragma unroll
            for (int kq = 0; kq < 16; kq++) {
                const float4 h4 = *(const float4*)&Hshc[ty * 68 + kq * 4];
                const float4 w0 = *(const float4*)&Wsc[(kq * 4 + 0) * 68 + tx * 4];
                const float4 w1 = *(const float4*)&Wsc[(kq * 4 + 1) * 68 + tx * 4];
                const float4 w2 = *(const float4*)&Wsc[(kq * 4 + 2) * 68 + tx * 4];
                const float4 w3 = *(const float4*)&Wsc[(kq * 4 + 3) * 68 + tx * 4];
                acc4[0] += h4.x * w0.x + h4.y * w1.x + h4.z * w2.x + h4.w * w3.x;
                acc4[1] += h4.x * w0.y + h4.y * w1.y + h4.z * w2.y + h4.w * w3.y;
                acc4[2] += h4.x * w0.z + h4.y * w1.z + h4.z * w2.z + h4.w * w3.z;
                acc4[3] += h4.x * w0.w + h4.y * w1.w + h4.z * w2.w + h4.w * w3.w;
            }
            __syncthreads();
        }
        const int hc = h0 + tx;
        const long xrow = (long)(ty * TCD + t) * 2048;
        const float gi = acc4[0] + xg[xrow + hc]        + bhh_c[hc];
        const float gf = acc4[1] + xg[xrow + 512 + hc]  + bhh_c[512 + hc];
        const float gg = acc4[2] + xg[xrow + 1024 + hc] + bhh_c[1024 + hc];
        const float go = acc4[3] + xg[xrow + 1536 + hc] + bhh_c[1536 + hc];
        const float c_old = cap_cst[(long)ty * 512 + hc];
        const float ii = sigf(gi), ff = sigf(gf), g2 = tanhfast(gg), oo = sigf(go);
        const float c = ff * c_old + ii * g2;
        const float h = oo * tanhfast(c);
        cap_cst[(long)ty * 512 + hc] = c;
        hc_out[(long)ty * 512 + hc] = h;
        cap_h[(long)(ty * TCD + t) * 512 + hc] = h;
        return;
    }

    // ---------------- video step ----------------
    const int n0 = (bx & 31) * 64;    // g' base
    const int b0 = (bx >> 5) * 32;    // batch base (16 tiles of 32)
    const int lane = tid & 63;
    const int w = tid >> 6;           // wave 0..3
    const int bi = w & 1;             // batch half (16 rows)
    const int nq = w >> 1;            // gate-pair: q = 2*nq + {0,1}
    const int lrow = lane & 15;
    const int lko = (lane >> 4) * 8;
    const int sra = tid >> 3;         // A staging row 0..31
    const int sca = (tid & 7) * 16;   // staging col base

    unsigned short* As = (unsigned short*)smem;           // [32][136] = 8704 B
    unsigned short* Ws = (unsigned short*)(smem + 8704);  // [64][136] = 17408 B

    const unsigned short* arow_vx = vx + ((long)(b0 + sra) * TVD + t) * 512;
    const unsigned short* arow_h  = h_in + (long)(b0 + sra) * 512;
    const unsigned short* wrow0   = Wcat + (long)(n0 + sra) * 1024;
    const unsigned short* wrow1   = Wcat + (long)(n0 + sra + 32) * 1024;

    f32x4 acc[2] = {};

    // stage chunk 0 (k 0..127, vx side)
    *(short8v*)&As[sra * 136 + sca]     = *(const short8v*)(arow_vx + sca);
    *(short8v*)&As[sra * 136 + sca + 8] = *(const short8v*)(arow_vx + sca + 8);
    *(short8v*)&Ws[sra * 136 + sca]            = *(const short8v*)(wrow0 + sca);
    *(short8v*)&Ws[sra * 136 + sca + 8]        = *(const short8v*)(wrow0 + sca + 8);
    *(short8v*)&Ws[(sra + 32) * 136 + sca]     = *(const short8v*)(wrow1 + sca);
    *(short8v*)&Ws[(sra + 32) * 136 + sca + 8] = *(const short8v*)(wrow1 + sca + 8);
    __syncthreads();

    short8v pa0, pa1, pw0, pw1, pw2, pw3;
    for (int c = 0; c < 8; c++) {
        if (c < 7) {
            const int k0 = (c + 1) * 128;
            const unsigned short* ap = (k0 < 512) ? (arow_vx + k0) : (arow_h + (k0 - 512));
            pa0 = *(const short8v*)(ap + sca);
            pa1 = *(const short8v*)(ap + sca + 8);
            pw0 = *(const short8v*)(wrow0 + k0 + sca);
            pw1 = *(const short8v*)(wrow0 + k0 + sca + 8);
            pw2 = *(const short8v*)(wrow1 + k0 + sca);
            pw3 = *(const short8v*)(wrow1 + k0 + sca + 8);
        }
#pragma unroll
        for (int kk = 0; kk < 4; kk++) {
            const short8v a = *(const short8v*)&As[(bi * 16 + lrow) * 136 + kk * 32 + lko];
#pragma unroll
            for (int nl = 0; nl < 2; nl++) {
                const short8v b = *(const short8v*)&Ws[((nq * 2 + nl) * 16 + lrow) * 136 + kk * 32 + lko];
                acc[nl] = __builtin_amdgcn_mfma_f32_16x16x32_bf16(a, b, acc[nl], 0, 0, 0);
            }
        }
        __syncthreads();
        if (c < 7) {
            *(short8v*)&As[sra * 136 + sca]            = pa0;
            *(short8v*)&As[sra * 136 + sca + 8]        = pa1;
            *(short8v*)&Ws[sra * 136 + sca]            = pw0;
            *(short8v*)&Ws[sra * 136 + sca + 8]        = pw1;
            *(short8v*)&Ws[(sra + 32) * 136 + sca]     = pw2;
            *(short8v*)&Ws[(sra + 32) * 136 + sca + 8] = pw3;
            __syncthreads();
        }
    }

    // gate exchange: waves 2,3 (q2,q3) -> LDS; waves 0,1 do cell update
    float* red = (float*)smem;   // [2][32][16] f32 = 4 KB (As region, done)
    const int rbase = (lane >> 4) * 4;
    if (w >= 2) {
#pragma unroll
        for (int nl = 0; nl < 2; nl++)
#pragma unroll
            for (int j = 0; j < 4; j++)
                red[nl * 512 + (bi * 16 + rbase + j) * 16 + lrow] = acc[nl][j];
    }
    __syncthreads();
    if (w < 2) {
        const int hc = (n0 >> 2) + lrow;
        const float bs0 = bsum[n0 + lrow];
        const float bs1 = bsum[n0 + 16 + lrow];
        const float bs2 = bsum[n0 + 32 + lrow];
        const float bs3 = bsum[n0 + 48 + lrow];
#pragma unroll
        for (int j = 0; j < 4; j++) {
            const int blocal = bi * 16 + rbase + j;
            const long b = b0 + blocal;
            const float gi = acc[0][j] + bs0;
            const float gf = acc[1][j] + bs1;
            const float gg = red[blocal * 16 + lrow] + bs2;
            const float go = red[512 + blocal * 16 + lrow] + bs3;
            const float c_old = c_state[b * 512 + hc];
            const float ii = sigf(gi), ff = sigf(gf), g2 = tanhfast(gg), oo = sigf(go);
            const float cn = ff * c_old + ii * g2;
            const float h = oo * tanhfast(cn);
            c_state[b * 512 + hc] = cn;
            h_out[b * 512 + hc] = f2bf(h);
            vid_h[(b * TVD + t) * 512 + hc] = f2bf(h);
        }
    }
}

// ---------------------------------------------------------------------------
// Generic fp32 tiled GEMM (cap front path + c_lin)
// ---------------------------------------------------------------------------
__launch_bounds__(256)
__global__ void gemm_bias_kernel(const float* __restrict__ A,
                                 const float* __restrict__ Bw,
                                 const float* __restrict__ bias,
                                 float* __restrict__ C,
                                 int M, int N, int K) {
    __shared__ float As[16][68];
    __shared__ float Bs[16][68];
    const int n0 = blockIdx.x * 64;
    const int m0 = blockIdx.y * 64;
    const int tid = threadIdx.x;
    const int tx = tid & 15;
    const int ty = tid >> 4;
    const int lrow = tid >> 2;
    const int lk4 = (tid & 3) * 4;

    float acc[4][4] = {};

    for (int k0 = 0; k0 < K; k0 += 16) {
        {
            const float* src = A + (long)(m0 + lrow) * K + k0 + lk4;
            float4 v;
            if (k0 + 16 <= K) v = *(const float4*)src;
            else {
                v.x = (k0 + lk4 + 0 < K) ? src[0] : 0.f;
                v.y = (k0 + lk4 + 1 < K) ? src[1] : 0.f;
                v.z = (k0 + lk4 + 2 < K) ? src[2] : 0.f;
                v.w = (k0 + lk4 + 3 < K) ? src[3] : 0.f;
            }
            As[lk4 + 0][lrow] = v.x; As[lk4 + 1][lrow] = v.y;
            As[lk4 + 2][lrow] = v.z; As[lk4 + 3][lrow] = v.w;
        }
        {
            const float* src = Bw + (long)(n0 + lrow) * K + k0 + lk4;
            float4 v;
            if (k0 + 16 <= K) v = *(const float4*)src;
            else {
                v.x = (k0 + lk4 + 0 < K) ? src[0] : 0.f;
                v.y = (k0 + lk4 + 1 < K) ? src[1] : 0.f;
                v.z = (k0 + lk4 + 2 < K) ? src[2] : 0.f;
                v.w = (k0 + lk4 + 3 < K) ? src[3] : 0.f;
            }
            Bs[lk4 + 0][lrow] = v.x; Bs[lk4 + 1][lrow] = v.y;
            Bs[lk4 + 2][lrow] = v.z; Bs[lk4 + 3][lrow] = v.w;
        }
        __syncthreads();
#pragma unroll
        for (int kk = 0; kk < 16; kk++) {
            const float4 av = *(const float4*)&As[kk][ty * 4];
            const float4 bv = *(const float4*)&Bs[kk][tx * 4];
            acc[0][0] += av.x * bv.x; acc[0][1] += av.x * bv.y; acc[0][2] += av.x * bv.z; acc[0][3] += av.x * bv.w;
            acc[1][0] += av.y * bv.x; acc[1][1] += av.y * bv.y; acc[1][2] += av.y * bv.z; acc[1][3] += av.y * bv.w;
            acc[2][0] += av.z * bv.x; acc[2][1] += av.z * bv.y; acc[2][2] += av.z * bv.z; acc[2][3] += av.z * bv.w;
            acc[3][0] += av.w * bv.x; acc[3][1] += av.w * bv.y; acc[3][2] += av.w * bv.z; acc[3][3] += av.w * bv.w;
        }
        __syncthreads();
    }

    const float b0v = bias[n0 + tx * 4 + 0];
    const float b1v = bias[n0 + tx * 4 + 1];
    const float b2v = bias[n0 + tx * 4 + 2];
    const float b3v = bias[n0 + tx * 4 + 3];
#pragma unroll
    for (int i = 0; i < 4; i++) {
        float* dst = C + (long)(m0 + ty * 4 + i) * N + n0 + tx * 4;
        dst[0] = acc[i][0] + b0v;
        dst[1] = acc[i][1] + b1v;
        dst[2] = acc[i][2] + b2v;
        dst[3] = acc[i][3] + b3v;
    }
}

// ---------------------------------------------------------------------------
// Attention + cap_ftr fused: one block per (bc, rp); scores -> masked softmax
// -> wbar (LDS) -> out2[br][h] = sum_t wbar[t]*cap_h[bc][t][h].
// ---------------------------------------------------------------------------
__launch_bounds__(256)
__global__ void attn_kernel(const float* __restrict__ v_lin,
                            const float* __restrict__ c_lin,
                            const float* __restrict__ W_att,
                            const float* __restrict__ b_att,
                            const int* __restrict__ cap_len,
                            const float* __restrict__ cap_h,
                            float* __restrict__ out2)
{
    const int br = blockIdx.x;
    const int bc = br >> 5;
    const int tid = threadIdx.x;
    const int lane = tid & 63;
    const int wv = tid >> 6;
    __shared__ float cl[TCD][AD];
    __shared__ float vl[AD];
    __shared__ float sl[TVD][TCD];
    __shared__ float wsum[TCD];

    for (int tt = 0; tt < TCD; tt++)
        cl[tt][tid] = c_lin[(long)(bc * TCD + tt) * AD + tid];
    const float wa0 = W_att[lane];
    const float wa1 = W_att[64 + lane];
    const float wa2 = W_att[128 + lane];
    const float wa3 = W_att[192 + lane];
    const float batt = b_att[0];
    __syncthreads();

    for (int v = 0; v < TVD; v++) {
        vl[tid] = v_lin[((long)br * TVD + v) * AD + tid];
        __syncthreads();
        const float v0 = vl[lane], v1 = vl[64 + lane], v2 = vl[128 + lane], v3 = vl[192 + lane];
#pragma unroll
        for (int dt = 0; dt < 5; dt++) {
            const int t = wv * 5 + dt;
            float s = tanhfast(v0 + cl[t][lane]) * wa0
                    + tanhfast(v1 + cl[t][64 + lane]) * wa1
                    + tanhfast(v2 + cl[t][128 + lane]) * wa2
                    + tanhfast(v3 + cl[t][192 + lane]) * wa3;
            for (int off = 32; off > 0; off >>= 1) s += __shfl_down(s, off, 64);
            if (lane == 0) sl[v][t] = s + batt;
        }
        __syncthreads();
    }

    int L = cap_len[bc];
    if (L < 1) L = 1;
    if (tid < TVD) {
        const int v = tid;
        float m = -1e30f;
        for (int t = 0; t < TCD; t++)
            if (t < L) m = fmaxf(m, sl[v][t]);
        float sum = 0.f;
        for (int t = 0; t < TCD; t++)
            if (t < L) sum += __expf(sl[v][t] - m);
        const float inv = 1.f / sum;
        for (int t = 0; t < TCD; t++)
            sl[v][t] = (t < L) ? __expf(sl[v][t] - m) * inv : 0.f;
    }
    __syncthreads();
    if (tid < TCD) {
        float s = 0.f;
        for (int v = 0; v < TVD; v++) s += sl[v][tid];
        wsum[tid] = s * (1.0f / TVD);
    }
    __syncthreads();

    const float* chb = cap_h + (long)bc * TCD * HD;
#pragma unroll
    for (int r = 0; r < 2; r++) {
        const int h = r * 256 + tid;
        float s = 0.f;
#pragma unroll
        for (int t = 0; t < TCD; t++)
            s += wsum[t] * chb[t * HD + h];
        out2[(long)br * HD + h] = s;
    }
}

// vid_mean from bf16 vid_h
__launch_bounds__(256)
__global__ void vidmean_bf_kernel(const unsigned short* __restrict__ vid_h,
                                  float* __restrict__ out1)
{
    const int idx = blockIdx.x * 256 + threadIdx.x;   // 0..32767
    const int b = idx >> 6;
    const int h8 = (idx & 63) * 8;
    float s[8] = {};
    for (int t = 0; t < TVD; t++) {
        const short8v v = *(const short8v*)(vid_h + ((long)b * TVD + t) * 512 + h8);
#pragma unroll
        for (int j = 0; j < 8; j++) s[j] += b2f((unsigned short)v[j]);
    }
#pragma unroll
    for (int j = 0; j < 8; j++)
        out1[(long)b * 512 + h8 + j] = s[j] * (1.0f / TVD);
}

extern "C" void kernel_launch(void* const* d_in, const int* in_sizes, int n_in,
                              void* d_out, int out_size, void* d_ws, size_t ws_size,
                              hipStream_t stream) {
    const float* video_fc      = (const float*)d_in[0];
    const float* video_caption = (const float*)d_in[1];
    const int*   cap_len       = (const int*)d_in[2];
    const float* W_vemb = (const float*)d_in[3];
    const float* b_vemb = (const float*)d_in[4];
    const float* W_wemb = (const float*)d_in[5];
    const float* b_wemb = (const float*)d_in[6];
    const float* Wih_v  = (const float*)d_in[7];
    const float* Whh_v  = (const float*)d_in[8];
    const float* bih_v  = (const float*)d_in[9];
    const float* bhh_v  = (const float*)d_in[10];
    const float* Wih_c  = (const float*)d_in[11];
    const float* Whh_c  = (const float*)d_in[12];
    const float* bih_c  = (const float*)d_in[13];
    const float* bhh_c  = (const float*)d_in[14];
    const float* W_vid  = (const float*)d_in[15];
    const float* b_vid  = (const float*)d_in[16];
    const float* W_sen  = (const float*)d_in[17];
    const float* b_sen  = (const float*)d_in[18];
    const float* W_att  = (const float*)d_in[19];
    const float* b_att  = (const float*)d_in[20];

    float* out1 = (float*)d_out;            // vid_mean
    float* out2 = out1 + BD * HD;           // cap_ftr_mean

    float* ws = (float*)d_ws;
    size_t off = 0;
    auto alloc = [&](size_t nfloats) {
        float* p = ws + off;
        off += (nfloats + 63) & ~(size_t)63;
        return p;
    };
    unsigned short* vidx_bf = (unsigned short*)alloc((size_t)BD * TVD * VEMBD / 2);
    unsigned short* vidh_bf = (unsigned short*)alloc((size_t)BD * TVD * HD / 2);
    unsigned short* h_bf_a  = (unsigned short*)alloc((size_t)BD * HD / 2);
    unsigned short* h_bf_b  = (unsigned short*)alloc((size_t)BD * HD / 2);
    float* c_st    = alloc((size_t)BD * HD);
    float* v_lin   = alloc((size_t)BD * TVD * AD);
    unsigned short* Wvemb_bf = (unsigned short*)alloc((size_t)VEMBD * FCD / 2);
    unsigned short* Wvid_bf  = (unsigned short*)alloc((size_t)AD * HD / 2);
    unsigned short* Wcat_bf  = (unsigned short*)alloc((size_t)2048 * 1024 / 2);
    float* bsum    = alloc(2048);
    float* cap_x   = alloc((size_t)BCD * TCD * WEMBD);
    float* xg_c    = alloc((size_t)BCD * TCD * 4 * HD);
    float* cap_h   = alloc((size_t)BCD * TCD * HD);
    float* c_lin   = alloc((size_t)BCD * TCD * AD);
    float* cap_ha  = alloc((size_t)BCD * HD);
    float* cap_hb  = alloc((size_t)BCD * HD);
    float* cap_cst = alloc((size_t)BCD * HD);
    // big optional buffer last: bf16 copy of video_fc (67 MB)
    const size_t fcn = (size_t)BD * TVD * FCD;   // elements
    const bool preconv = ((off + fcn / 2 + 64) * sizeof(float) <= ws_size);
    unsigned short* vidfc_bf = preconv ? (unsigned short*)alloc(fcn / 2) : nullptr;

    hipMemsetAsync(h_bf_a, 0, (size_t)BD * HD * sizeof(unsigned short), stream);
    hipMemsetAsync(c_st, 0, (size_t)BD * HD * sizeof(float), stream);
    hipMemsetAsync(cap_ha, 0, (size_t)BCD * HD * sizeof(float), stream);
    hipMemsetAsync(cap_cst, 0, (size_t)BCD * HD * sizeof(float), stream);

    // weight conversions
    conv_f2b_kernel<<<512, 256, 0, stream>>>(W_vemb, Wvemb_bf, VEMBD * FCD / 4);
    conv_f2b_kernel<<<128, 256, 0, stream>>>(W_vid, Wvid_bf, AD * HD / 4);
    conv_wcat_perm_kernel<<<2048, 256, 0, stream>>>(Wih_v, Whh_v, Wcat_bf);
    conv_bsum_kernel<<<8, 256, 0, stream>>>(bih_v, bhh_v, bsum);

    // caption front path (fp32)
    gemm_bias_kernel<<<dim3(WEMBD / 64, (BCD * TCD) / 64), 256, 0, stream>>>(
        video_caption, W_wemb, b_wemb, cap_x, BCD * TCD, WEMBD, GLOVED);
    gemm_bias_kernel<<<dim3((4 * HD) / 64, (BCD * TCD) / 64), 256, 0, stream>>>(
        cap_x, Wih_c, bih_c, xg_c, BCD * TCD, 4 * HD, WEMBD);

    // vid_x GEMM (bf16 MFMA, m-fastest grid); pre-convert A when ws allows
    if (preconv) {
        conv_f2b_kernel<<<2048, 256, 0, stream>>>(video_fc, vidfc_bf, (int)(fcn / 4));
        mfma_gemm128<0, 1><<<dim3((BD * TVD) / 128, VEMBD / 128), 256, 0, stream>>>(
            vidfc_bf, Wvemb_bf, b_vemb, vidx_bf, BD * TVD, VEMBD, FCD);
    } else {
        mfma_gemm128<1, 1><<<dim3((BD * TVD) / 128, VEMBD / 128), 256, 0, stream>>>(
            video_fc, Wvemb_bf, b_vemb, vidx_bf, BD * TVD, VEMBD, FCD);
    }

    // fused LSTM steps: vid blocks 0..511 (2/CU), cap blocks 512..543 (t<20)
    for (int t = 0; t < TVD; t++) {
        const unsigned short* hin = (t & 1) ? h_bf_b : h_bf_a;
        unsigned short* hout = (t & 1) ? h_bf_a : h_bf_b;
        const float* chin = (t & 1) ? cap_hb : cap_ha;
        float* chout = (t & 1) ? cap_ha : cap_hb;
        const int nblk = (t < TCD) ? 544 : 512;
        step_fused<<<nblk, 256, 0, stream>>>(
            vidx_bf, hin, hout, Wcat_bf, bsum, c_st, vidh_bf, t,
            xg_c, Whh_c, bhh_c, chin, chout, cap_cst, cap_h);
    }

    // post GEMMs
    gemm_bias_kernel<<<dim3(AD / 64, (BCD * TCD) / 64), 256, 0, stream>>>(
        cap_h, W_sen, b_sen, c_lin, BCD * TCD, AD, HD);
    mfma_gemm128<0, 0><<<dim3((BD * TVD) / 128, AD / 128), 256, 0, stream>>>(
        vidh_bf, Wvid_bf, b_vid, v_lin, BD * TVD, AD, HD);

    // attention (+cap_ftr fused) + vid mean
    attn_kernel<<<BD, 256, 0, stream>>>(v_lin, c_lin, W_att, b_att, cap_len, cap_h, out2);
    vidmean_bf_kernel<<<(BD * HD / 8) / 256, 256, 0, stream>>>(vidh_bf, out1);
}